// Round 5
// baseline (1271.596 us; speedup 1.0000x reference)
//
#include <hip/hip_runtime.h>
#include <hip/hip_bf16.h>
#include <math.h>

// RWKV-7 Tmix forward, MI355X/gfx950.
// B=2 T=1024 C=2048 H=32 N=64. Outputs: xo [B,T,C], x[:,-1] [B,C], S_final [B,H,N,N].

#define B_ 2
#define T_ 1024
#define C_ 2048
#define H_ 32
#define BT_ (B_*T_)
#define BTC_ ((size_t)BT_*C_)
#define CC_ ((size_t)C_*C_)
#define KS_ 8            // split-K factor for stage-1 GEMMs

typedef __bf16 bf16x8 __attribute__((ext_vector_type(8)));
typedef float f32x4 __attribute__((ext_vector_type(4)));

__device__ __forceinline__ float wave64_sum(float v){
#pragma unroll
  for (int d = 1; d < 64; d <<= 1) v += __shfl_xor(v, d, 64);
  return v;
}

// ---------------- fp32 -> bf16 convert ----------------
__global__ __launch_bounds__(256) void f2bf_kernel(const float* __restrict__ in,
                                                   __hip_bfloat16* __restrict__ out, size_t n){
  size_t i = (size_t)blockIdx.x*256 + threadIdx.x;
  if (i < n) out[i] = __float2bfloat16(in[i]);
}

// ---------------- token shift: xx fp32, xmx bf16 ----------------
__global__ __launch_bounds__(256) void shift_kernel(const float* __restrict__ x,
                                                    const float* __restrict__ shift,
                                                    const float* __restrict__ maa_x,
                                                    float* __restrict__ xx, __hip_bfloat16* __restrict__ xmx_h){
  size_t idx = (size_t)blockIdx.x*256 + threadIdx.x;  // over BTC
  int c = (int)(idx % C_);
  size_t bt = idx / C_;
  int t = (int)(bt % T_);
  int b = (int)(bt / T_);
  float xv = x[idx];
  float prev = (t == 0) ? shift[(size_t)b*C_ + c] : x[idx - C_];
  float d = prev - xv;
  xx[idx] = d;
  xmx_h[idx] = __float2bfloat16(xv + d * maa_x[c]);
}

// ---------------- transpose+convert: W[K=2048,Nsrc] fp32 -> rows [row_off..) of Wt[128,2048] bf16 ----------------
__global__ __launch_bounds__(256) void tp_pack(const float* __restrict__ in, __hip_bfloat16* __restrict__ out,
                                               int Nsrc, int row_off){
  __shared__ float tile[32][33];
  const int t = threadIdx.x;
  const int k0 = blockIdx.x*32, n0 = blockIdx.y*32;
  const int tn = t & 31, tk = t >> 5;  // tk 0..7
#pragma unroll
  for (int q = 0; q < 4; q++){
    int ki = tk + 8*q;
    float v = (n0 + tn < Nsrc) ? in[(size_t)(k0+ki)*Nsrc + n0 + tn] : 0.f;
    tile[tn][ki] = v;
  }
  __syncthreads();
#pragma unroll
  for (int q = 0; q < 4; q++){
    int no = tk + 8*q;
    if (n0 + no < Nsrc)
      out[(size_t)(row_off + n0 + no)*2048 + k0 + tn] = __float2bfloat16(tile[no][tn]);
  }
}

// ---------------- split-K skinny MFMA GEMM: parts[z] = A[128rows x KC] * B[128, KC]^T ----------------
__global__ __launch_bounds__(256) void gemm_sk(const __hip_bfloat16* __restrict__ Ah,
                                               const __hip_bfloat16* __restrict__ Bh,
                                               float* __restrict__ parts, int K, int KC){
  __shared__ __bf16 As[128*40];
  __shared__ __bf16 Bs[128*40];
  const int tid = threadIdx.x;
  const int bm = blockIdx.x*128;
  const int z = blockIdx.y;
  const int wid = tid >> 6, lane = tid & 63;
  const int wr = (wid >> 1)*64, wc = (wid & 1)*64;
  const int fr = lane & 15, kg = lane >> 4;
  const int srow = tid >> 2, sk = (tid & 3)*8;
  f32x4 acc[4][4] = {};
  const int kend = z*KC + KC;
  for (int kt = z*KC; kt < kend; kt += 32){
    __syncthreads();
    uint4 a0 = *(const uint4*)(Ah + (size_t)(bm+srow)*K + kt + sk);
    uint4 a1 = *(const uint4*)(Ah + (size_t)(bm+srow+64)*K + kt + sk);
    uint4 b0 = *(const uint4*)(Bh + (size_t)(srow)*K + kt + sk);
    uint4 b1 = *(const uint4*)(Bh + (size_t)(srow+64)*K + kt + sk);
    *(uint4*)(As + srow*40 + sk)      = a0;
    *(uint4*)(As + (srow+64)*40 + sk) = a1;
    *(uint4*)(Bs + srow*40 + sk)      = b0;
    *(uint4*)(Bs + (srow+64)*40 + sk) = b1;
    __syncthreads();
    bf16x8 af[4], bfr[4];
#pragma unroll
    for (int i = 0; i < 4; i++){
      af[i]  = *(const bf16x8*)(As + (wr + i*16 + fr)*40 + kg*8);
      bfr[i] = *(const bf16x8*)(Bs + (wc + i*16 + fr)*40 + kg*8);
    }
#pragma unroll
    for (int mi = 0; mi < 4; mi++)
#pragma unroll
      for (int ni = 0; ni < 4; ni++)
        acc[mi][ni] = __builtin_amdgcn_mfma_f32_16x16x32_bf16(af[mi], bfr[ni], acc[mi][ni], 0, 0, 0);
  }
  float* Cc = parts + (size_t)z*BT_*128;
  const int orow0 = bm + wr + kg*4;
  const int ocol0 = wc + fr;
#pragma unroll
  for (int mi = 0; mi < 4; mi++)
#pragma unroll
    for (int ni = 0; ni < 4; ni++)
#pragma unroll
      for (int j = 0; j < 4; j++)
        Cc[(size_t)(orow0 + mi*16 + j)*128 + ocol0 + ni*16] = acc[mi][ni][j];
}

// ---------------- reduce split-K parts + fused tanh on column range ----------------
__global__ __launch_bounds__(256) void reduce_sk(const float* __restrict__ parts, float* __restrict__ out,
                                                 int tanh_lo, int tanh_hi){
  size_t idx = (size_t)blockIdx.x*256 + threadIdx.x;  // BT*128
  float s = 0.f;
#pragma unroll
  for (int z = 0; z < KS_; z++) s += parts[(size_t)z*BT_*128 + idx];
  int c = (int)(idx & 127);
  if (c >= tanh_lo && c < tanh_hi) s = tanhf(s);
  out[idx] = s;
}

// ---------------- g = tanh'd g1[BT,128] @ gw2[128,C] -> bf16 ----------------
__global__ __launch_bounds__(256) void mm_sk_g(const float* __restrict__ A, const float* __restrict__ W,
                                               __hip_bfloat16* __restrict__ out, int K){
  const int j = blockIdx.y*256 + threadIdx.x;
  const int i0 = blockIdx.x*8;
  float acc[8] = {0,0,0,0,0,0,0,0};
  for (int k = 0; k < K; k++){
    float wv = W[(size_t)k*C_ + j];
#pragma unroll
    for (int r = 0; r < 8; r++) acc[r] += A[(size_t)(i0+r)*K + k] * wv;
  }
#pragma unroll
  for (int r = 0; r < 8; r++) out[(size_t)(i0+r)*C_ + j] = __float2bfloat16(acc[r]);
}

// ---------------- maa einsum + mix -> bf16 xrg/xwa/xk/xv ----------------
__global__ __launch_bounds__(256) void mix_kernel(
    const float* __restrict__ m1, const float* __restrict__ w2,
    const float* __restrict__ x, const float* __restrict__ xx,
    const float* __restrict__ maa_rg, const float* __restrict__ maa_wa,
    const float* __restrict__ maa_k, const float* __restrict__ maa_v,
    __hip_bfloat16* __restrict__ xrg_h, __hip_bfloat16* __restrict__ xwa_h,
    __hip_bfloat16* __restrict__ xk_h, __hip_bfloat16* __restrict__ xv_h)
{
  const int j = blockIdx.y*256 + threadIdx.x;
  const int i0 = blockIdx.x*8;
  float acc[4][8] = {};
#pragma unroll
  for (int f = 0; f < 4; f++){
    for (int d = 0; d < 32; d++){
      float wv = w2[((size_t)f*32 + d)*C_ + j];
#pragma unroll
      for (int r = 0; r < 8; r++)
        acc[f][r] += m1[(size_t)(i0+r)*128 + f*32 + d] * wv;
    }
  }
  float mrg_ = maa_rg[j], mwa_ = maa_wa[j], mk_ = maa_k[j], mv_ = maa_v[j];
#pragma unroll
  for (int r = 0; r < 8; r++){
    size_t idx = (size_t)(i0+r)*C_ + j;
    float xval = x[idx], xxv = xx[idx];
    xrg_h[idx] = __float2bfloat16(xval + xxv*(mrg_ + acc[0][r]));
    xwa_h[idx] = __float2bfloat16(xval + xxv*(mwa_ + acc[1][r]));
    xk_h[idx]  = __float2bfloat16(xval + xxv*(mk_  + acc[2][r]));
    xv_h[idx]  = __float2bfloat16(xval + xxv*(mv_  + acc[3][r]));
  }
}

// ---------------- bf16 MFMA GEMM: C[M,N] = A[M,K] * B[N,K]^T (fp32 out) ----------------
__global__ __launch_bounds__(256) void gemm_bt(const __hip_bfloat16* __restrict__ Ah,
                                               const __hip_bfloat16* __restrict__ Bh,
                                               float* __restrict__ Cc, int M, int Nn, int K){
  __shared__ __bf16 As[128*40];
  __shared__ __bf16 Bs[128*40];
  const int tid = threadIdx.x;
  const int bm = blockIdx.x*128, bn = blockIdx.y*128;
  const int wid = tid >> 6, lane = tid & 63;
  const int wr = (wid >> 1)*64, wc = (wid & 1)*64;
  const int fr = lane & 15, kg = lane >> 4;
  const int srow = tid >> 2, sk = (tid & 3)*8;
  f32x4 acc[4][4] = {};
  for (int kt = 0; kt < K; kt += 32){
    __syncthreads();
    uint4 a0 = *(const uint4*)(Ah + (size_t)(bm+srow)*K + kt + sk);
    uint4 a1 = *(const uint4*)(Ah + (size_t)(bm+srow+64)*K + kt + sk);
    uint4 b0 = *(const uint4*)(Bh + (size_t)(bn+srow)*K + kt + sk);
    uint4 b1 = *(const uint4*)(Bh + (size_t)(bn+srow+64)*K + kt + sk);
    *(uint4*)(As + srow*40 + sk)      = a0;
    *(uint4*)(As + (srow+64)*40 + sk) = a1;
    *(uint4*)(Bs + srow*40 + sk)      = b0;
    *(uint4*)(Bs + (srow+64)*40 + sk) = b1;
    __syncthreads();
    bf16x8 af[4], bfr[4];
#pragma unroll
    for (int i = 0; i < 4; i++){
      af[i]  = *(const bf16x8*)(As + (wr + i*16 + fr)*40 + kg*8);
      bfr[i] = *(const bf16x8*)(Bs + (wc + i*16 + fr)*40 + kg*8);
    }
#pragma unroll
    for (int mi = 0; mi < 4; mi++)
#pragma unroll
      for (int ni = 0; ni < 4; ni++)
        acc[mi][ni] = __builtin_amdgcn_mfma_f32_16x16x32_bf16(af[mi], bfr[ni], acc[mi][ni], 0, 0, 0);
  }
  const int orow0 = bm + wr + kg*4;
  const int ocol0 = bn + wc + fr;
#pragma unroll
  for (int mi = 0; mi < 4; mi++)
#pragma unroll
    for (int ni = 0; ni < 4; ni++)
#pragma unroll
      for (int j = 0; j < 4; j++)
        Cc[(size_t)(orow0 + mi*16 + j)*Nn + ocol0 + ni*16] = acc[mi][ni][j];
}

// ---------------- fused LoRA stage-2 + decay/gates elementwise ----------------
// wa1[BT,128]: cols 0..63 = tanh(d1), 64..79 = a1, 80..95 = ma1
// k1c[BT,128]: cols 0..15 = tanh(kk1), 16..31 = mk1
__global__ __launch_bounds__(256) void lora2_kernel(
    const float* __restrict__ wa1, const float* __restrict__ k1c,
    const float* __restrict__ dw2, const float* __restrict__ aw2, const float* __restrict__ maw2,
    const float* __restrict__ mkw2, const float* __restrict__ kkw2,
    const float* __restrict__ td, const float* __restrict__ aaaaa,
    const float* __restrict__ misc_a, const float* __restrict__ misc_k,
    float* __restrict__ k0,                    // in: raw k  out: final k
    float* __restrict__ a_out, float* __restrict__ ew_out, float* __restrict__ kk0_out)
{
  const int j = blockIdx.y*256 + threadIdx.x;
  const int i0 = blockIdx.x*8;
  float accW[8] = {}, accA[8] = {}, accMA[8] = {}, accMK[8] = {}, accKK[8] = {};
  for (int k = 0; k < 64; k++){
    float wv = dw2[(size_t)k*C_ + j];
#pragma unroll
    for (int r = 0; r < 8; r++) accW[r] += wa1[(size_t)(i0+r)*128 + k] * wv;
  }
  for (int k = 0; k < 16; k++){
    float w_a  = aw2[(size_t)k*C_ + j];
    float w_ma = maw2[(size_t)k*C_ + j];
    float w_mk = mkw2[(size_t)k*C_ + j];
    float w_kk = kkw2[(size_t)k*C_ + j];
#pragma unroll
    for (int r = 0; r < 8; r++){
      accA[r]  += wa1[(size_t)(i0+r)*128 + 64 + k] * w_a;
      accMA[r] += wa1[(size_t)(i0+r)*128 + 80 + k] * w_ma;
      accKK[r] += k1c[(size_t)(i0+r)*128 + k] * w_kk;
      accMK[r] += k1c[(size_t)(i0+r)*128 + 16 + k] * w_mk;
    }
  }
  float tdv = td[j], aav = aaaaa[j], mav = misc_a[j], mkv = misc_k[j];
#pragma unroll
  for (int r = 0; r < 8; r++){
    size_t idx = (size_t)(i0+r)*C_ + j;
    float u  = tdv + accW[r];
    float w  = -log1pf(expf(-u)) - 0.5f;               // -softplus(-u) - 0.5
    float a  = 1.f/(1.f + expf(-(aav + accA[r])));
    float ma = 1.f/(1.f + expf(-(mav + accMA[r])));
    float mk = 1.f/(1.f + expf(-(mkv + accMK[r])));
    float kv = k0[idx];
    kk0_out[idx] = kv + accKK[r];
    float kn = kv * (ma + a*(1.f - ma)) * expf(fminf(w*mk, 0.f));
    k0[idx] = kn;
    a_out[idx] = a;
    ew_out[idx] = expf(w);
  }
}

// ---------------- kk normalize per head + b = kk*a (in-place) ----------------
__global__ __launch_bounds__(256) void kknorm_kernel(float* __restrict__ kk0, float* __restrict__ a_bs){
  const size_t grp = (size_t)blockIdx.x*4 + (threadIdx.x >> 6);
  const int lane = threadIdx.x & 63;
  const size_t idx = grp*64 + lane;
  float kv = kk0[idx];
  float ss = wave64_sum(kv*kv);
  float nrm = fmaxf(sqrtf(ss), 1e-12f);
  float kkn = kv / nrm;
  kk0[idx] = kkn;
  a_bs[idx] = kkn * a_bs[idx];
}

// ---------------- RWKV-7 recurrence: 64 blocks (b,h) x 256 threads (4 waves) ----------------
// 4 waves of a block = 4 v-chunks of the same (b,h): they read IDENTICAL k-vector data,
// so after one wave's miss the others hit L1 (per-step working set 1.3 KB << 32 KB L1).
// No barriers; waves drift freely. 4-deep register pipeline; OOB prefetches (t+4..t+6)
// land in subsequent allocated ws buffers - never consumed.
struct SR { float4 a[4], e[4], k[4], b[4], r[4]; float vt; };

__device__ __forceinline__ void rec_load(SR& s,
    const float* __restrict__ rr, const float* __restrict__ kx, const float* __restrict__ vx,
    const float* __restrict__ ew, const float* __restrict__ kkv, const float* __restrict__ bsv,
    size_t base, int t, int kq16, int v){
  const size_t off = base + (size_t)t*(H_*64);
  const size_t ko = off + kq16;
#pragma unroll
  for (int q = 0; q < 4; q++){
    s.a[q] = *(const float4*)(kkv + ko + 4*q);
    s.e[q] = *(const float4*)(ew  + ko + 4*q);
    s.k[q] = *(const float4*)(kx  + ko + 4*q);
    s.b[q] = *(const float4*)(bsv + ko + 4*q);
    s.r[q] = *(const float4*)(rr  + ko + 4*q);
  }
  s.vt = vx[off + v];
}

__device__ __forceinline__ void rec_cmp(const SR& s, float S[16],
    float* __restrict__ o, size_t base, int t, int v, int kq){
  // 4 independent partial chains (dependent-FMA depth 4 instead of 16)
  float p0, p1, p2, p3;
  p0  = s.a[0].x*S[0];  p0 += s.a[0].y*S[1];  p0 += s.a[0].z*S[2];  p0 += s.a[0].w*S[3];
  p1  = s.a[1].x*S[4];  p1 += s.a[1].y*S[5];  p1 += s.a[1].z*S[6];  p1 += s.a[1].w*S[7];
  p2  = s.a[2].x*S[8];  p2 += s.a[2].y*S[9];  p2 += s.a[2].z*S[10]; p2 += s.a[2].w*S[11];
  p3  = s.a[3].x*S[12]; p3 += s.a[3].y*S[13]; p3 += s.a[3].z*S[14]; p3 += s.a[3].w*S[15];
  float sap = (p0+p1) + (p2+p3);
  sap += __shfl_xor(sap, 16, 64);
  sap += __shfl_xor(sap, 32, 64);
  const float sa = -sap;            // a_t = -kk
  const float vt = s.vt;
  float o0, o1, o2, o3;
  S[0]  = S[0] *s.e[0].x + s.k[0].x*vt + s.b[0].x*sa; o0  = s.r[0].x*S[0];
  S[1]  = S[1] *s.e[0].y + s.k[0].y*vt + s.b[0].y*sa; o0 += s.r[0].y*S[1];
  S[2]  = S[2] *s.e[0].z + s.k[0].z*vt + s.b[0].z*sa; o0 += s.r[0].z*S[2];
  S[3]  = S[3] *s.e[0].w + s.k[0].w*vt + s.b[0].w*sa; o0 += s.r[0].w*S[3];
  S[4]  = S[4] *s.e[1].x + s.k[1].x*vt + s.b[1].x*sa; o1  = s.r[1].x*S[4];
  S[5]  = S[5] *s.e[1].y + s.k[1].y*vt + s.b[1].y*sa; o1 += s.r[1].y*S[5];
  S[6]  = S[6] *s.e[1].z + s.k[1].z*vt + s.b[1].z*sa; o1 += s.r[1].z*S[6];
  S[7]  = S[7] *s.e[1].w + s.k[1].w*vt + s.b[1].w*sa; o1 += s.r[1].w*S[7];
  S[8]  = S[8] *s.e[2].x + s.k[2].x*vt + s.b[2].x*sa; o2  = s.r[2].x*S[8];
  S[9]  = S[9] *s.e[2].y + s.k[2].y*vt + s.b[2].y*sa; o2 += s.r[2].y*S[9];
  S[10] = S[10]*s.e[2].z + s.k[2].z*vt + s.b[2].z*sa; o2 += s.r[2].z*S[10];
  S[11] = S[11]*s.e[2].w + s.k[2].w*vt + s.b[2].w*sa; o2 += s.r[2].w*S[11];
  S[12] = S[12]*s.e[3].x + s.k[3].x*vt + s.b[3].x*sa; o3  = s.r[3].x*S[12];
  S[13] = S[13]*s.e[3].y + s.k[3].y*vt + s.b[3].y*sa; o3 += s.r[3].y*S[13];
  S[14] = S[14]*s.e[3].z + s.k[3].z*vt + s.b[3].z*sa; o3 += s.r[3].z*S[14];
  S[15] = S[15]*s.e[3].w + s.k[3].w*vt + s.b[3].w*sa; o3 += s.r[3].w*S[15];
  float op = (o0+o1) + (o2+o3);
  op += __shfl_xor(op, 16, 64);
  op += __shfl_xor(op, 32, 64);
  if (kq == 0) o[base + (size_t)t*(H_*64) + v] = op;
}

__global__ __launch_bounds__(256, 1) void rec_kernel(
    const float* __restrict__ rr, const float* __restrict__ kx,
    const float* __restrict__ vx, const float* __restrict__ ew,
    const float* __restrict__ kkv, const float* __restrict__ bsv,
    const float* __restrict__ s0, float* __restrict__ o, float* __restrict__ sT)
{
  const int bh = blockIdx.x;           // 64 blocks
  const int b = bh >> 5, h = bh & 31;
  const int wid = threadIdx.x >> 6;    // v-chunk 0..3
  const int lane = threadIdx.x & 63;
  const int v = wid*16 + (lane & 15);
  const int kq = lane >> 4;
  const int kq16 = kq*16;
  float S[16];
  {
    const float* p = s0 + ((size_t)bh*64 + kq16)*64 + v;
#pragma unroll
    for (int i = 0; i < 16; i++) S[i] = p[(size_t)i*64];
  }
  const size_t base = (size_t)b*T_*(H_*64) + (size_t)h*64;

  SR s0r, s1r, s2r, s3r;
  rec_load(s0r, rr, kx, vx, ew, kkv, bsv, base, 0, kq16, v);
  rec_load(s1r, rr, kx, vx, ew, kkv, bsv, base, 1, kq16, v);
  rec_load(s2r, rr, kx, vx, ew, kkv, bsv, base, 2, kq16, v);
  for (int t = 0; t < T_; t += 4){
    rec_load(s3r, rr, kx, vx, ew, kkv, bsv, base, t+3, kq16, v);
    rec_cmp(s0r, S, o, base, t+0, v, kq);
    rec_load(s0r, rr, kx, vx, ew, kkv, bsv, base, t+4, kq16, v);
    rec_cmp(s1r, S, o, base, t+1, v, kq);
    rec_load(s1r, rr, kx, vx, ew, kkv, bsv, base, t+5, kq16, v);
    rec_cmp(s2r, S, o, base, t+2, v, kq);
    rec_load(s2r, rr, kx, vx, ew, kkv, bsv, base, t+6, kq16, v);
    rec_cmp(s3r, S, o, base, t+3, v, kq);
  }
  float* p = sT + ((size_t)bh*64 + kq16)*64 + v;
#pragma unroll
  for (int i = 0; i < 16; i++) p[(size_t)i*64] = S[i];
}

// ---------------- GroupNorm + faaaa term + *g -> z (bf16) ----------------
__global__ __launch_bounds__(256) void post_kernel(
    const float* __restrict__ o, const float* __restrict__ r, const float* __restrict__ k,
    const float* __restrict__ v, const __hip_bfloat16* __restrict__ g,
    const float* __restrict__ lnw, const float* __restrict__ lnb,
    const float* __restrict__ faaaa, __hip_bfloat16* __restrict__ z_h)
{
  const size_t grp = (size_t)blockIdx.x*4 + (threadIdx.x >> 6);
  const int lane = threadIdx.x & 63;
  const int h = (int)(grp & (H_-1));
  const size_t idx = grp*64 + lane;
  const int ci = h*64 + lane;
  float y = o[idx];
  float mu = wave64_sum(y) * (1.f/64.f);
  float d = y - mu;
  float var = wave64_sum(d*d) * (1.f/64.f);
  float yn = d * rsqrtf(var + 64e-5f) * lnw[ci] + lnb[ci];
  float s = wave64_sum(r[idx]*k[idx]*faaaa[ci]);
  float xo = yn + s*v[idx];
  z_h[idx] = __float2bfloat16(xo * __bfloat162float(g[idx]));
}

// ---------------- x[:, -1] ----------------
__global__ __launch_bounds__(256) void lastx_kernel(const float* __restrict__ x, float* __restrict__ out1){
  int idx = blockIdx.x*256 + threadIdx.x;   // B*C
  int b = idx / C_, c = idx % C_;
  out1[idx] = x[((size_t)b*T_ + (T_-1))*C_ + c];
}

extern "C" void kernel_launch(void* const* d_in, const int* in_sizes, int n_in,
                              void* d_out, int out_size, void* d_ws, size_t ws_size,
                              hipStream_t stream){
  (void)in_sizes; (void)n_in; (void)out_size;
  const float* x      = (const float*)d_in[0];
  const float* shift  = (const float*)d_in[1];
  const float* wkv0   = (const float*)d_in[2];
  const float* maa_x  = (const float*)d_in[3];
  const float* maa_rg = (const float*)d_in[4];
  const float* maa_wa = (const float*)d_in[5];
  const float* maa_k  = (const float*)d_in[6];
  const float* maa_v  = (const float*)d_in[7];
  const float* maa_w1 = (const float*)d_in[8];
  const float* maa_w2 = (const float*)d_in[9];
  const float* tdecay = (const float*)d_in[10];
  const float* dw1    = (const float*)d_in[11];
  const float* dw2    = (const float*)d_in[12];
  const float* faaaa  = (const float*)d_in[13];
  const float* aaaaa  = (const float*)d_in[14];
  const float* aw1    = (const float*)d_in[15];
  const float* aw2    = (const float*)d_in[16];
  const float* kkw1   = (const float*)d_in[17];
  const float* kkw2   = (const float*)d_in[18];
  const float* gw1    = (const float*)d_in[19];
  const float* gw2    = (const float*)d_in[20];
  const float* maw1   = (const float*)d_in[21];
  const float* maw2   = (const float*)d_in[22];
  const float* misc_a = (const float*)d_in[23];
  const float* mkw1   = (const float*)d_in[24];
  const float* mkw2   = (const float*)d_in[25];
  const float* misc_k = (const float*)d_in[26];
  const float* Wr     = (const float*)d_in[27];
  const float* Wk     = (const float*)d_in[28];
  const float* Wv     = (const float*)d_in[29];
  const float* Wo     = (const float*)d_in[30];
  const float* lnw    = (const float*)d_in[31];
  const float* lnb    = (const float*)d_in[32];

  float* out0 = (float*)d_out;                 // [B,T,C]  (also holds o pre-epilogue)
  float* out1 = out0 + BTC_;                   // [B,C]
  float* outS = out1 + (size_t)B_*C_;          // [B,H,N,N]

  // ---- workspace layout ----
  // fp32: rbuf kbuf vbuf abuf ewbuf kkbuf (6*BTC) | wa1 g1f k1c (3*BT*128)
  // bf16: xrg_h | xwa_h(->g_h) | xk_h | xv_h(->xmx_h,->z_h) | Wb (5*CC) | WtB (4*128*2048)
  // aliases: parts(split-K, 8*BT*128 fp32) = rbuf ; m1f = vbuf ;
  //          Wk_h = (bf16)ewbuf ; Wv_h = (bf16)kkbuf (both dead until lora2)
  const size_t NEEDED = (6*BTC_ + (size_t)3*BT_*128)*4 + 5*CC_*2 + (size_t)4*128*2048*2;
  if (ws_size < NEEDED) return;

  float* ws = (float*)d_ws;
  float* rbuf  = ws;
  float* kbuf  = ws + 1*BTC_;
  float* vbuf  = ws + 2*BTC_;
  float* abuf  = ws + 3*BTC_;   // a -> b_s ; early alias: xx
  float* ewbuf = ws + 4*BTC_;   // exp(w)   ; early alias: Wk_h
  float* kkbuf = ws + 5*BTC_;   // kk0 -> kk; early alias: Wv_h
  float* xx    = abuf;
  float* wa1   = ws + 6*BTC_;                    // [BT,128]
  float* g1f   = wa1 + (size_t)BT_*128;          // [BT,128]
  float* k1c   = g1f + (size_t)BT_*128;          // [BT,128]
  float* parts = rbuf;                           // [KS][BT,128]
  float* m1f   = vbuf;                           // [BT,128]
  __hip_bfloat16* hb = (__hip_bfloat16*)(k1c + (size_t)BT_*128);
  __hip_bfloat16* xrg_h = hb;
  __hip_bfloat16* xwa_h = hb + 1*CC_;
  __hip_bfloat16* xk_h  = hb + 2*CC_;
  __hip_bfloat16* xv_h  = hb + 3*CC_;
  __hip_bfloat16* Wb    = hb + 4*CC_;
  __hip_bfloat16* WtB   = hb + 5*CC_;            // 4 x [128,2048]
  __hip_bfloat16* Wt_m  = WtB;
  __hip_bfloat16* Wt_wa = WtB + (size_t)128*2048;
  __hip_bfloat16* Wt_g  = WtB + (size_t)2*128*2048;
  __hip_bfloat16* Wt_k  = WtB + (size_t)3*128*2048;
  __hip_bfloat16* xmx_h = xv_h;   // consumed by m1 GEMM before mix writes xv_h
  __hip_bfloat16* g_h   = xwa_h;  // xwa_h dead after its stage-1 GEMM
  __hip_bfloat16* z_h   = xv_h;   // xv_h dead after v GEMM
  __hip_bfloat16* Wk_h  = (__hip_bfloat16*)ewbuf;
  __hip_bfloat16* Wv_h  = (__hip_bfloat16*)kkbuf;

  dim3 blk(256);
  const int KC = C_/KS_;   // 256

  // zero the packed-weight region (covers zero-padding rows)
  hipMemsetAsync(WtB, 0, (size_t)4*128*2048*2, stream);
  // pack stage-1 weights: transpose+convert into [128,2048] bf16
  tp_pack<<<dim3(64,4), blk, 0, stream>>>(maa_w1, Wt_m, 128, 0);
  tp_pack<<<dim3(64,2), blk, 0, stream>>>(dw1,  Wt_wa, 64, 0);
  tp_pack<<<dim3(64,1), blk, 0, stream>>>(aw1,  Wt_wa, 16, 64);
  tp_pack<<<dim3(64,1), blk, 0, stream>>>(maw1, Wt_wa, 16, 80);
  tp_pack<<<dim3(64,4), blk, 0, stream>>>(gw1,  Wt_g, 128, 0);
  tp_pack<<<dim3(64,1), blk, 0, stream>>>(kkw1, Wt_k, 16, 0);
  tp_pack<<<dim3(64,1), blk, 0, stream>>>(mkw1, Wt_k, 16, 16);

  // token shift (xx fp32 into abuf, xmx bf16 into xv_h slot)
  shift_kernel<<<(int)(BTC_/256), blk, 0, stream>>>(x, shift, maa_x, xx, xmx_h);

  // m1 = tanh(xmx @ maa_w1): split-K MFMA + reduce
  gemm_sk<<<dim3(BT_/128, KS_), blk, 0, stream>>>(xmx_h, Wt_m, parts, C_, KC);
  reduce_sk<<<BT_*128/256, blk, 0, stream>>>(parts, m1f, 0, 128);

  // mix -> xrg/xwa/xk/xv bf16 (overwrites xmx_h slot with xv_h)
  mix_kernel<<<dim3(BT_/8, C_/256), blk, 0, stream>>>(m1f, maa_w2, x, xx, maa_rg, maa_wa, maa_k, maa_v,
                                                      xrg_h, xwa_h, xk_h, xv_h);
  // stage-1 LoRA GEMMs
  gemm_sk<<<dim3(BT_/128, KS_), blk, 0, stream>>>(xwa_h, Wt_wa, parts, C_, KC);
  reduce_sk<<<BT_*128/256, blk, 0, stream>>>(parts, wa1, 0, 64);      // tanh on d1 cols
  gemm_sk<<<dim3(BT_/128, KS_), blk, 0, stream>>>(xrg_h, Wt_g, parts, C_, KC);
  reduce_sk<<<BT_*128/256, blk, 0, stream>>>(parts, g1f, 0, 128);     // tanh all
  gemm_sk<<<dim3(BT_/128, KS_), blk, 0, stream>>>(xk_h, Wt_k, parts, C_, KC);
  reduce_sk<<<BT_*128/256, blk, 0, stream>>>(parts, k1c, 0, 16);      // tanh on kk1 cols

  // g (overwrites xwa_h slot)
  mm_sk_g<<<dim3(BT_/8, C_/256), blk, 0, stream>>>(g1f, gw2, g_h, 128);

  // weight conversions up-front (Wk_h/Wv_h live in ewbuf/kkbuf, dead until lora2),
  // then the three big GEMMs back-to-back
  f2bf_kernel<<<(int)(CC_/256), blk, 0, stream>>>(Wr, Wb, CC_);
  f2bf_kernel<<<(int)(CC_/256), blk, 0, stream>>>(Wk, Wk_h, CC_);
  f2bf_kernel<<<(int)(CC_/256), blk, 0, stream>>>(Wv, Wv_h, CC_);
  gemm_bt<<<dim3(BT_/128, C_/128), blk, 0, stream>>>(xrg_h, Wb,   rbuf, BT_, C_, C_);
  gemm_bt<<<dim3(BT_/128, C_/128), blk, 0, stream>>>(xk_h,  Wk_h, kbuf, BT_, C_, C_);
  gemm_bt<<<dim3(BT_/128, C_/128), blk, 0, stream>>>(xv_h,  Wv_h, vbuf, BT_, C_, C_);

  // LoRA stage 2 fused + elementwise (overwrites ewbuf/kkbuf), then kk normalize
  lora2_kernel<<<dim3(BT_/8, C_/256), blk, 0, stream>>>(wa1, k1c,
                                                        dw2, aw2, maw2, mkw2, kkw2,
                                                        tdecay, aaaaa, misc_a, misc_k,
                                                        kbuf, abuf, ewbuf, kkbuf);
  kknorm_kernel<<<BT_*H_/4, blk, 0, stream>>>(kkbuf, abuf);

  // recurrence: 64 blocks x 256 threads (o into out0, overwritten by final GEMM)
  rec_kernel<<<B_*H_, blk, 0, stream>>>(rbuf, kbuf, vbuf, ewbuf, kkbuf, abuf, wkv0, out0, outS);

  // groupnorm + faaaa + gate -> z_h (bf16), final GEMM, last-x copy
  post_kernel<<<BT_*H_/4, blk, 0, stream>>>(out0, rbuf, kbuf, vbuf, g_h, lnw, lnb, faaaa, z_h);
  f2bf_kernel<<<(int)(CC_/256), blk, 0, stream>>>(Wo, Wb, CC_);
  gemm_bt<<<dim3(BT_/128, C_/128), blk, 0, stream>>>(z_h, Wb, out0, BT_, C_, C_);
  lastx_kernel<<<(B_*C_)/256, blk, 0, stream>>>(x, out1);
}

// Round 6
// 1085.021 us; speedup vs baseline: 1.1720x; 1.1720x over previous
//
#include <hip/hip_runtime.h>
#include <hip/hip_bf16.h>
#include <math.h>

// RWKV-7 Tmix forward, MI355X/gfx950.
// B=2 T=1024 C=2048 H=32 N=64. Outputs: xo [B,T,C], x[:,-1] [B,C], S_final [B,H,N,N].
// R6: rec inputs in [B,H,T,N] layout + LDS-ring recurrence via global_load_lds.

#define B_ 2
#define T_ 1024
#define C_ 2048
#define H_ 32
#define BT_ (B_*T_)
#define BTC_ ((size_t)BT_*C_)
#define CC_ ((size_t)C_*C_)
#define KS_ 8            // split-K factor for stage-1 GEMMs
#define CH_ 16           // rec chunk (steps per LDS stage)

typedef __bf16 bf16x8 __attribute__((ext_vector_type(8)));
typedef float f32x4 __attribute__((ext_vector_type(4)));

__device__ __forceinline__ float wave64_sum(float v){
#pragma unroll
  for (int d = 1; d < 64; d <<= 1) v += __shfl_xor(v, d, 64);
  return v;
}

// bhtn index helper: (b,t) row r in [BT), channel c in [C) -> [B,H,T,64]
__device__ __forceinline__ size_t bhtn_idx(int r, int c){
  return (((size_t)(r >> 10)*H_ + (c >> 6))*T_ + (r & 1023))*64 + (c & 63);
}

// ---------------- fp32 -> bf16 convert ----------------
__global__ __launch_bounds__(256) void f2bf_kernel(const float* __restrict__ in,
                                                   __hip_bfloat16* __restrict__ out, size_t n){
  size_t i = (size_t)blockIdx.x*256 + threadIdx.x;
  if (i < n) out[i] = __float2bfloat16(in[i]);
}

// ---------------- token shift: xx fp32, xmx bf16 ----------------
__global__ __launch_bounds__(256) void shift_kernel(const float* __restrict__ x,
                                                    const float* __restrict__ shift,
                                                    const float* __restrict__ maa_x,
                                                    float* __restrict__ xx, __hip_bfloat16* __restrict__ xmx_h){
  size_t idx = (size_t)blockIdx.x*256 + threadIdx.x;  // over BTC
  int c = (int)(idx % C_);
  size_t bt = idx / C_;
  int t = (int)(bt % T_);
  int b = (int)(bt / T_);
  float xv = x[idx];
  float prev = (t == 0) ? shift[(size_t)b*C_ + c] : x[idx - C_];
  float d = prev - xv;
  xx[idx] = d;
  xmx_h[idx] = __float2bfloat16(xv + d * maa_x[c]);
}

// ---------------- transpose+convert: W[K=2048,Nsrc] fp32 -> rows [row_off..) of Wt[128,2048] bf16 ----------------
__global__ __launch_bounds__(256) void tp_pack(const float* __restrict__ in, __hip_bfloat16* __restrict__ out,
                                               int Nsrc, int row_off){
  __shared__ float tile[32][33];
  const int t = threadIdx.x;
  const int k0 = blockIdx.x*32, n0 = blockIdx.y*32;
  const int tn = t & 31, tk = t >> 5;  // tk 0..7
#pragma unroll
  for (int q = 0; q < 4; q++){
    int ki = tk + 8*q;
    float v = (n0 + tn < Nsrc) ? in[(size_t)(k0+ki)*Nsrc + n0 + tn] : 0.f;
    tile[tn][ki] = v;
  }
  __syncthreads();
#pragma unroll
  for (int q = 0; q < 4; q++){
    int no = tk + 8*q;
    if (n0 + no < Nsrc)
      out[(size_t)(row_off + n0 + no)*2048 + k0 + tn] = __float2bfloat16(tile[no][tn]);
  }
}

// ---------------- split-K skinny MFMA GEMM: parts[z] = A[128rows x KC] * B[128, KC]^T ----------------
__global__ __launch_bounds__(256) void gemm_sk(const __hip_bfloat16* __restrict__ Ah,
                                               const __hip_bfloat16* __restrict__ Bh,
                                               float* __restrict__ parts, int K, int KC){
  __shared__ __bf16 As[128*40];
  __shared__ __bf16 Bs[128*40];
  const int tid = threadIdx.x;
  const int bm = blockIdx.x*128;
  const int z = blockIdx.y;
  const int wid = tid >> 6, lane = tid & 63;
  const int wr = (wid >> 1)*64, wc = (wid & 1)*64;
  const int fr = lane & 15, kg = lane >> 4;
  const int srow = tid >> 2, sk = (tid & 3)*8;
  f32x4 acc[4][4] = {};
  const int kend = z*KC + KC;
  for (int kt = z*KC; kt < kend; kt += 32){
    __syncthreads();
    uint4 a0 = *(const uint4*)(Ah + (size_t)(bm+srow)*K + kt + sk);
    uint4 a1 = *(const uint4*)(Ah + (size_t)(bm+srow+64)*K + kt + sk);
    uint4 b0 = *(const uint4*)(Bh + (size_t)(srow)*K + kt + sk);
    uint4 b1 = *(const uint4*)(Bh + (size_t)(srow+64)*K + kt + sk);
    *(uint4*)(As + srow*40 + sk)      = a0;
    *(uint4*)(As + (srow+64)*40 + sk) = a1;
    *(uint4*)(Bs + srow*40 + sk)      = b0;
    *(uint4*)(Bs + (srow+64)*40 + sk) = b1;
    __syncthreads();
    bf16x8 af[4], bfr[4];
#pragma unroll
    for (int i = 0; i < 4; i++){
      af[i]  = *(const bf16x8*)(As + (wr + i*16 + fr)*40 + kg*8);
      bfr[i] = *(const bf16x8*)(Bs + (wc + i*16 + fr)*40 + kg*8);
    }
#pragma unroll
    for (int mi = 0; mi < 4; mi++)
#pragma unroll
      for (int ni = 0; ni < 4; ni++)
        acc[mi][ni] = __builtin_amdgcn_mfma_f32_16x16x32_bf16(af[mi], bfr[ni], acc[mi][ni], 0, 0, 0);
  }
  float* Cc = parts + (size_t)z*BT_*128;
  const int orow0 = bm + wr + kg*4;
  const int ocol0 = wc + fr;
#pragma unroll
  for (int mi = 0; mi < 4; mi++)
#pragma unroll
    for (int ni = 0; ni < 4; ni++)
#pragma unroll
      for (int j = 0; j < 4; j++)
        Cc[(size_t)(orow0 + mi*16 + j)*128 + ocol0 + ni*16] = acc[mi][ni][j];
}

// ---------------- reduce split-K parts + fused tanh on column range ----------------
__global__ __launch_bounds__(256) void reduce_sk(const float* __restrict__ parts, float* __restrict__ out,
                                                 int tanh_lo, int tanh_hi){
  size_t idx = (size_t)blockIdx.x*256 + threadIdx.x;  // BT*128
  float s = 0.f;
#pragma unroll
  for (int z = 0; z < KS_; z++) s += parts[(size_t)z*BT_*128 + idx];
  int c = (int)(idx & 127);
  if (c >= tanh_lo && c < tanh_hi) s = tanhf(s);
  out[idx] = s;
}

// ---------------- g = tanh'd g1[BT,128] @ gw2[128,C] -> bf16 ----------------
__global__ __launch_bounds__(256) void mm_sk_g(const float* __restrict__ A, const float* __restrict__ W,
                                               __hip_bfloat16* __restrict__ out, int K){
  const int j = blockIdx.y*256 + threadIdx.x;
  const int i0 = blockIdx.x*8;
  float acc[8] = {0,0,0,0,0,0,0,0};
  for (int k = 0; k < K; k++){
    float wv = W[(size_t)k*C_ + j];
#pragma unroll
    for (int r = 0; r < 8; r++) acc[r] += A[(size_t)(i0+r)*K + k] * wv;
  }
#pragma unroll
  for (int r = 0; r < 8; r++) out[(size_t)(i0+r)*C_ + j] = __float2bfloat16(acc[r]);
}

// ---------------- maa einsum + mix -> bf16 xrg/xwa/xk/xv ----------------
__global__ __launch_bounds__(256) void mix_kernel(
    const float* __restrict__ m1, const float* __restrict__ w2,
    const float* __restrict__ x, const float* __restrict__ xx,
    const float* __restrict__ maa_rg, const float* __restrict__ maa_wa,
    const float* __restrict__ maa_k, const float* __restrict__ maa_v,
    __hip_bfloat16* __restrict__ xrg_h, __hip_bfloat16* __restrict__ xwa_h,
    __hip_bfloat16* __restrict__ xk_h, __hip_bfloat16* __restrict__ xv_h)
{
  const int j = blockIdx.y*256 + threadIdx.x;
  const int i0 = blockIdx.x*8;
  float acc[4][8] = {};
#pragma unroll
  for (int f = 0; f < 4; f++){
    for (int d = 0; d < 32; d++){
      float wv = w2[((size_t)f*32 + d)*C_ + j];
#pragma unroll
      for (int r = 0; r < 8; r++)
        acc[f][r] += m1[(size_t)(i0+r)*128 + f*32 + d] * wv;
    }
  }
  float mrg_ = maa_rg[j], mwa_ = maa_wa[j], mk_ = maa_k[j], mv_ = maa_v[j];
#pragma unroll
  for (int r = 0; r < 8; r++){
    size_t idx = (size_t)(i0+r)*C_ + j;
    float xval = x[idx], xxv = xx[idx];
    xrg_h[idx] = __float2bfloat16(xval + xxv*(mrg_ + acc[0][r]));
    xwa_h[idx] = __float2bfloat16(xval + xxv*(mwa_ + acc[1][r]));
    xk_h[idx]  = __float2bfloat16(xval + xxv*(mk_  + acc[2][r]));
    xv_h[idx]  = __float2bfloat16(xval + xxv*(mv_  + acc[3][r]));
  }
}

// ---------------- bf16 MFMA GEMM: C[M,N] = A[M,K] * B[N,K]^T (fp32 out, btc layout) ----------------
__global__ __launch_bounds__(256) void gemm_bt(const __hip_bfloat16* __restrict__ Ah,
                                               const __hip_bfloat16* __restrict__ Bh,
                                               float* __restrict__ Cc, int M, int Nn, int K){
  __shared__ __bf16 As[128*40];
  __shared__ __bf16 Bs[128*40];
  const int tid = threadIdx.x;
  const int bm = blockIdx.x*128, bn = blockIdx.y*128;
  const int wid = tid >> 6, lane = tid & 63;
  const int wr = (wid >> 1)*64, wc = (wid & 1)*64;
  const int fr = lane & 15, kg = lane >> 4;
  const int srow = tid >> 2, sk = (tid & 3)*8;
  f32x4 acc[4][4] = {};
  for (int kt = 0; kt < K; kt += 32){
    __syncthreads();
    uint4 a0 = *(const uint4*)(Ah + (size_t)(bm+srow)*K + kt + sk);
    uint4 a1 = *(const uint4*)(Ah + (size_t)(bm+srow+64)*K + kt + sk);
    uint4 b0 = *(const uint4*)(Bh + (size_t)(bn+srow)*K + kt + sk);
    uint4 b1 = *(const uint4*)(Bh + (size_t)(bn+srow+64)*K + kt + sk);
    *(uint4*)(As + srow*40 + sk)      = a0;
    *(uint4*)(As + (srow+64)*40 + sk) = a1;
    *(uint4*)(Bs + srow*40 + sk)      = b0;
    *(uint4*)(Bs + (srow+64)*40 + sk) = b1;
    __syncthreads();
    bf16x8 af[4], bfr[4];
#pragma unroll
    for (int i = 0; i < 4; i++){
      af[i]  = *(const bf16x8*)(As + (wr + i*16 + fr)*40 + kg*8);
      bfr[i] = *(const bf16x8*)(Bs + (wc + i*16 + fr)*40 + kg*8);
    }
#pragma unroll
    for (int mi = 0; mi < 4; mi++)
#pragma unroll
      for (int ni = 0; ni < 4; ni++)
        acc[mi][ni] = __builtin_amdgcn_mfma_f32_16x16x32_bf16(af[mi], bfr[ni], acc[mi][ni], 0, 0, 0);
  }
  const int orow0 = bm + wr + kg*4;
  const int ocol0 = bn + wc + fr;
#pragma unroll
  for (int mi = 0; mi < 4; mi++)
#pragma unroll
    for (int ni = 0; ni < 4; ni++)
#pragma unroll
      for (int j = 0; j < 4; j++)
        Cc[(size_t)(orow0 + mi*16 + j)*Nn + ocol0 + ni*16] = acc[mi][ni][j];
}

// ---------------- same GEMM but writes C in [B,H,T,64] (bhtn) layout ----------------
__global__ __launch_bounds__(256) void gemm_bt_T(const __hip_bfloat16* __restrict__ Ah,
                                                 const __hip_bfloat16* __restrict__ Bh,
                                                 float* __restrict__ Cc, int K){
  __shared__ __bf16 As[128*40];
  __shared__ __bf16 Bs[128*40];
  const int tid = threadIdx.x;
  const int bm = blockIdx.x*128, bn = blockIdx.y*128;
  const int wid = tid >> 6, lane = tid & 63;
  const int wr = (wid >> 1)*64, wc = (wid & 1)*64;
  const int fr = lane & 15, kg = lane >> 4;
  const int srow = tid >> 2, sk = (tid & 3)*8;
  f32x4 acc[4][4] = {};
  for (int kt = 0; kt < K; kt += 32){
    __syncthreads();
    uint4 a0 = *(const uint4*)(Ah + (size_t)(bm+srow)*K + kt + sk);
    uint4 a1 = *(const uint4*)(Ah + (size_t)(bm+srow+64)*K + kt + sk);
    uint4 b0 = *(const uint4*)(Bh + (size_t)(bn+srow)*K + kt + sk);
    uint4 b1 = *(const uint4*)(Bh + (size_t)(bn+srow+64)*K + kt + sk);
    *(uint4*)(As + srow*40 + sk)      = a0;
    *(uint4*)(As + (srow+64)*40 + sk) = a1;
    *(uint4*)(Bs + srow*40 + sk)      = b0;
    *(uint4*)(Bs + (srow+64)*40 + sk) = b1;
    __syncthreads();
    bf16x8 af[4], bfr[4];
#pragma unroll
    for (int i = 0; i < 4; i++){
      af[i]  = *(const bf16x8*)(As + (wr + i*16 + fr)*40 + kg*8);
      bfr[i] = *(const bf16x8*)(Bs + (wc + i*16 + fr)*40 + kg*8);
    }
#pragma unroll
    for (int mi = 0; mi < 4; mi++)
#pragma unroll
      for (int ni = 0; ni < 4; ni++)
        acc[mi][ni] = __builtin_amdgcn_mfma_f32_16x16x32_bf16(af[mi], bfr[ni], acc[mi][ni], 0, 0, 0);
  }
  const int r0 = bm + wr + kg*4;
  const int c0 = bn + wc + fr;
#pragma unroll
  for (int mi = 0; mi < 4; mi++)
#pragma unroll
    for (int ni = 0; ni < 4; ni++)
#pragma unroll
      for (int j = 0; j < 4; j++)
        Cc[bhtn_idx(r0 + mi*16 + j, c0 + ni*16)] = acc[mi][ni][j];
}

// ---------------- fused LoRA stage-2 + decay/gates elementwise (writes bhtn) ----------------
// wa1[BT,128]: cols 0..63 = tanh(d1), 64..79 = a1, 80..95 = ma1
// k1c[BT,128]: cols 0..15 = tanh(kk1), 16..31 = mk1
// k0/a_out/ew_out/kk0_out are in [B,H,T,64] layout.
__global__ __launch_bounds__(256) void lora2_kernel(
    const float* __restrict__ wa1, const float* __restrict__ k1c,
    const float* __restrict__ dw2, const float* __restrict__ aw2, const float* __restrict__ maw2,
    const float* __restrict__ mkw2, const float* __restrict__ kkw2,
    const float* __restrict__ td, const float* __restrict__ aaaaa,
    const float* __restrict__ misc_a, const float* __restrict__ misc_k,
    float* __restrict__ k0, float* __restrict__ a_out,
    float* __restrict__ ew_out, float* __restrict__ kk0_out)
{
  const int j = blockIdx.y*256 + threadIdx.x;
  const int i0 = blockIdx.x*8;
  float accW[8] = {}, accA[8] = {}, accMA[8] = {}, accMK[8] = {}, accKK[8] = {};
  for (int k = 0; k < 64; k++){
    float wv = dw2[(size_t)k*C_ + j];
#pragma unroll
    for (int r = 0; r < 8; r++) accW[r] += wa1[(size_t)(i0+r)*128 + k] * wv;
  }
  for (int k = 0; k < 16; k++){
    float w_a  = aw2[(size_t)k*C_ + j];
    float w_ma = maw2[(size_t)k*C_ + j];
    float w_mk = mkw2[(size_t)k*C_ + j];
    float w_kk = kkw2[(size_t)k*C_ + j];
#pragma unroll
    for (int r = 0; r < 8; r++){
      accA[r]  += wa1[(size_t)(i0+r)*128 + 64 + k] * w_a;
      accMA[r] += wa1[(size_t)(i0+r)*128 + 80 + k] * w_ma;
      accKK[r] += k1c[(size_t)(i0+r)*128 + k] * w_kk;
      accMK[r] += k1c[(size_t)(i0+r)*128 + 16 + k] * w_mk;
    }
  }
  float tdv = td[j], aav = aaaaa[j], mav = misc_a[j], mkv = misc_k[j];
#pragma unroll
  for (int r = 0; r < 8; r++){
    size_t idx = bhtn_idx(i0+r, j);
    float u  = tdv + accW[r];
    float w  = -log1pf(expf(-u)) - 0.5f;               // -softplus(-u) - 0.5
    float a  = 1.f/(1.f + expf(-(aav + accA[r])));
    float ma = 1.f/(1.f + expf(-(mav + accMA[r])));
    float mk = 1.f/(1.f + expf(-(mkv + accMK[r])));
    float kv = k0[idx];
    kk0_out[idx] = kv + accKK[r];
    float kn = kv * (ma + a*(1.f - ma)) * expf(fminf(w*mk, 0.f));
    k0[idx] = kn;
    a_out[idx] = a;
    ew_out[idx] = expf(w);
  }
}

// ---------------- kk normalize per head + b = kk*a (in-place; bhtn-compatible) ----------------
__global__ __launch_bounds__(256) void kknorm_kernel(float* __restrict__ kk0, float* __restrict__ a_bs){
  const size_t grp = (size_t)blockIdx.x*4 + (threadIdx.x >> 6);
  const int lane = threadIdx.x & 63;
  const size_t idx = grp*64 + lane;
  float kv = kk0[idx];
  float ss = wave64_sum(kv*kv);
  float nrm = fmaxf(sqrtf(ss), 1e-12f);
  float kkn = kv / nrm;
  kk0[idx] = kkn;
  a_bs[idx] = kkn * a_bs[idx];
}

// ---------------- RWKV-7 recurrence: 256 blocks x 64 threads, LDS ring ----------------
// block = (bh, v-chunk). Streams in [B,H,T,64] layout -> per-chunk staging is a straight
// 4KB copy per stream via global_load_lds (64 lanes x 16B x 4). Double buffer, manual
// s_waitcnt vmcnt(24): safe whether or not stores count (vmcnt retires in order).
__device__ __forceinline__ void gload_lds16(const float* g, float* l){
  __builtin_amdgcn_global_load_lds((const __attribute__((address_space(1))) void*)g,
                                   (__attribute__((address_space(3))) void*)l, 16, 0, 0);
}

__global__ __launch_bounds__(64, 1) void rec_kernel(
    const float* __restrict__ rr, const float* __restrict__ kx,
    const float* __restrict__ vx, const float* __restrict__ ew,
    const float* __restrict__ kkv, const float* __restrict__ bsv,
    const float* __restrict__ s0, float* __restrict__ o, float* __restrict__ sT)
{
  __shared__ __align__(16) float lds[2][6][CH_*64];
  const int blk = blockIdx.x;          // 256 = bh*4 + vc
  const int bh = blk >> 2, vc = blk & 3;
  const int b = bh >> 5, h = bh & 31;
  const int lane = threadIdx.x;
  const int fr = lane & 15, kq = lane >> 4, kq16 = kq*16;
  const int v = vc*16 + fr;

  float S[16];
  {
    const float* p = s0 + ((size_t)bh*64 + kq16)*64 + v;
#pragma unroll
    for (int i = 0; i < 16; i++) S[i] = p[(size_t)i*64];
  }

  const size_t sb = (size_t)bh*T_*64;  // stream base (bhtn)
  const float* g0 = kkv + sb;  // a
  const float* g1 = ew  + sb;  // e
  const float* g2 = kx  + sb;  // k
  const float* g3 = bsv + sb;  // b
  const float* g4 = rr  + sb;  // r
  const float* g5 = vx  + sb;  // v
  float* ob = o + (size_t)b*T_*C_ + h*64 + v;   // + t*C_

  // stage chunk c into buffer buf: 6 streams x 4 x (64 lanes x 16B)
#define STAGE(c, buf) do{ \
    const size_t co_ = (size_t)(c)*(CH_*64) + lane*4; \
    _Pragma("unroll") \
    for (int j_ = 0; j_ < 4; j_++){ \
      gload_lds16(g0 + co_ + j_*256, &lds[buf][0][j_*256]); \
      gload_lds16(g1 + co_ + j_*256, &lds[buf][1][j_*256]); \
      gload_lds16(g2 + co_ + j_*256, &lds[buf][2][j_*256]); \
      gload_lds16(g3 + co_ + j_*256, &lds[buf][3][j_*256]); \
      gload_lds16(g4 + co_ + j_*256, &lds[buf][4][j_*256]); \
      gload_lds16(g5 + co_ + j_*256, &lds[buf][5][j_*256]); \
    } }while(0)

  STAGE(0, 0);
  const int NCH = T_/CH_;              // 64
  for (int c = 0; c < NCH; c++){
    const int cn = (c+1 < NCH) ? c+1 : c;   // harmless re-stage on last iter
    STAGE(cn, (c+1)&1);
    __builtin_amdgcn_s_waitcnt(0x4F78);     // vmcnt(24): chunk c's 24 loads complete
    __builtin_amdgcn_sched_barrier(0);      // keep ds_reads below the wait
    const int buf = c & 1;
#pragma unroll 4
    for (int s = 0; s < CH_; s++){
      const int so = s*64 + kq16;
      float4 A[4], E[4], Kk[4], Bv[4], R[4];
#pragma unroll
      for (int q = 0; q < 4; q++){
        A[q]  = *(const float4*)(&lds[buf][0][so + 4*q]);
        E[q]  = *(const float4*)(&lds[buf][1][so + 4*q]);
        Kk[q] = *(const float4*)(&lds[buf][2][so + 4*q]);
        Bv[q] = *(const float4*)(&lds[buf][3][so + 4*q]);
        R[q]  = *(const float4*)(&lds[buf][4][so + 4*q]);
      }
      const float vt = lds[buf][5][s*64 + v];
      float p0, p1, p2, p3;
      p0  = A[0].x*S[0];  p0 += A[0].y*S[1];  p0 += A[0].z*S[2];  p0 += A[0].w*S[3];
      p1  = A[1].x*S[4];  p1 += A[1].y*S[5];  p1 += A[1].z*S[6];  p1 += A[1].w*S[7];
      p2  = A[2].x*S[8];  p2 += A[2].y*S[9];  p2 += A[2].z*S[10]; p2 += A[2].w*S[11];
      p3  = A[3].x*S[12]; p3 += A[3].y*S[13]; p3 += A[3].z*S[14]; p3 += A[3].w*S[15];
      float sap = (p0+p1) + (p2+p3);
      sap += __shfl_xor(sap, 16, 64);
      sap += __shfl_xor(sap, 32, 64);
      const float sa = -sap;               // a_t = -kk
      float o0, o1, o2, o3;
      S[0]  = S[0] *E[0].x + Kk[0].x*vt + Bv[0].x*sa; o0  = R[0].x*S[0];
      S[1]  = S[1] *E[0].y + Kk[0].y*vt + Bv[0].y*sa; o0 += R[0].y*S[1];
      S[2]  = S[2] *E[0].z + Kk[0].z*vt + Bv[0].z*sa; o0 += R[0].z*S[2];
      S[3]  = S[3] *E[0].w + Kk[0].w*vt + Bv[0].w*sa; o0 += R[0].w*S[3];
      S[4]  = S[4] *E[1].x + Kk[1].x*vt + Bv[1].x*sa; o1  = R[1].x*S[4];
      S[5]  = S[5] *E[1].y + Kk[1].y*vt + Bv[1].y*sa; o1 += R[1].y*S[5];
      S[6]  = S[6] *E[1].z + Kk[1].z*vt + Bv[1].z*sa; o1 += R[1].z*S[6];
      S[7]  = S[7] *E[1].w + Kk[1].w*vt + Bv[1].w*sa; o1 += R[1].w*S[7];
      S[8]  = S[8] *E[2].x + Kk[2].x*vt + Bv[2].x*sa; o2  = R[2].x*S[8];
      S[9]  = S[9] *E[2].y + Kk[2].y*vt + Bv[2].y*sa; o2 += R[2].y*S[9];
      S[10] = S[10]*E[2].z + Kk[2].z*vt + Bv[2].z*sa; o2 += R[2].z*S[10];
      S[11] = S[11]*E[2].w + Kk[2].w*vt + Bv[2].w*sa; o2 += R[2].w*S[11];
      S[12] = S[12]*E[3].x + Kk[3].x*vt + Bv[3].x*sa; o3  = R[3].x*S[12];
      S[13] = S[13]*E[3].y + Kk[3].y*vt + Bv[3].y*sa; o3 += R[3].y*S[13];
      S[14] = S[14]*E[3].z + Kk[3].z*vt + Bv[3].z*sa; o3 += R[3].z*S[14];
      S[15] = S[15]*E[3].w + Kk[3].w*vt + Bv[3].w*sa; o3 += R[3].w*S[15];
      float op = (o0+o1) + (o2+o3);
      op += __shfl_xor(op, 16, 64);
      op += __shfl_xor(op, 32, 64);
      if (kq == 0) ob[(size_t)(c*CH_ + s)*C_] = op;
    }
  }
#undef STAGE
  float* p = sT + ((size_t)bh*64 + kq16)*64 + v;
#pragma unroll
  for (int i = 0; i < 16; i++) p[(size_t)i*64] = S[i];
}

// ---------------- GroupNorm + faaaa term + *g -> z (bf16) ----------------
// o,g,z in btc layout; r,k,v in bhtn layout.
__global__ __launch_bounds__(256) void post_kernel(
    const float* __restrict__ o, const float* __restrict__ r, const float* __restrict__ k,
    const float* __restrict__ v, const __hip_bfloat16* __restrict__ g,
    const float* __restrict__ lnw, const float* __restrict__ lnb,
    const float* __restrict__ faaaa, __hip_bfloat16* __restrict__ z_h)
{
  const size_t grp = (size_t)blockIdx.x*4 + (threadIdx.x >> 6);  // bt*H + h
  const int lane = threadIdx.x & 63;
  const int h = (int)(grp & (H_-1));
  const int bt = (int)(grp >> 5);
  const size_t idx  = grp*64 + lane;                              // btc
  const size_t idx2 = (((size_t)(bt >> 10)*H_ + h)*T_ + (bt & 1023))*64 + lane;  // bhtn
  const int ci = h*64 + lane;
  float y = o[idx];
  float mu = wave64_sum(y) * (1.f/64.f);
  float d = y - mu;
  float var = wave64_sum(d*d) * (1.f/64.f);
  float yn = d * rsqrtf(var + 64e-5f) * lnw[ci] + lnb[ci];
  float s = wave64_sum(r[idx2]*k[idx2]*faaaa[ci]);
  float xo = yn + s*v[idx2];
  z_h[idx] = __float2bfloat16(xo * __bfloat162float(g[idx]));
}

// ---------------- x[:, -1] ----------------
__global__ __launch_bounds__(256) void lastx_kernel(const float* __restrict__ x, float* __restrict__ out1){
  int idx = blockIdx.x*256 + threadIdx.x;   // B*C
  int b = idx / C_, c = idx % C_;
  out1[idx] = x[((size_t)b*T_ + (T_-1))*C_ + c];
}

extern "C" void kernel_launch(void* const* d_in, const int* in_sizes, int n_in,
                              void* d_out, int out_size, void* d_ws, size_t ws_size,
                              hipStream_t stream){
  (void)in_sizes; (void)n_in; (void)out_size;
  const float* x      = (const float*)d_in[0];
  const float* shift  = (const float*)d_in[1];
  const float* wkv0   = (const float*)d_in[2];
  const float* maa_x  = (const float*)d_in[3];
  const float* maa_rg = (const float*)d_in[4];
  const float* maa_wa = (const float*)d_in[5];
  const float* maa_k  = (const float*)d_in[6];
  const float* maa_v  = (const float*)d_in[7];
  const float* maa_w1 = (const float*)d_in[8];
  const float* maa_w2 = (const float*)d_in[9];
  const float* tdecay = (const float*)d_in[10];
  const float* dw1    = (const float*)d_in[11];
  const float* dw2    = (const float*)d_in[12];
  const float* faaaa  = (const float*)d_in[13];
  const float* aaaaa  = (const float*)d_in[14];
  const float* aw1    = (const float*)d_in[15];
  const float* aw2    = (const float*)d_in[16];
  const float* kkw1   = (const float*)d_in[17];
  const float* kkw2   = (const float*)d_in[18];
  const float* gw1    = (const float*)d_in[19];
  const float* gw2    = (const float*)d_in[20];
  const float* maw1   = (const float*)d_in[21];
  const float* maw2   = (const float*)d_in[22];
  const float* misc_a = (const float*)d_in[23];
  const float* mkw1   = (const float*)d_in[24];
  const float* mkw2   = (const float*)d_in[25];
  const float* misc_k = (const float*)d_in[26];
  const float* Wr     = (const float*)d_in[27];
  const float* Wk     = (const float*)d_in[28];
  const float* Wv     = (const float*)d_in[29];
  const float* Wo     = (const float*)d_in[30];
  const float* lnw    = (const float*)d_in[31];
  const float* lnb    = (const float*)d_in[32];

  float* out0 = (float*)d_out;                 // [B,T,C]  (also holds o pre-epilogue)
  float* out1 = out0 + BTC_;                   // [B,C]
  float* outS = out1 + (size_t)B_*C_;          // [B,H,N,N]

  const size_t NEEDED = (6*BTC_ + (size_t)3*BT_*128)*4 + 5*CC_*2 + (size_t)4*128*2048*2;
  if (ws_size < NEEDED) return;

  float* ws = (float*)d_ws;
  float* rbuf  = ws;            // bhtn
  float* kbuf  = ws + 1*BTC_;   // bhtn
  float* vbuf  = ws + 2*BTC_;   // bhtn
  float* abuf  = ws + 3*BTC_;   // a -> b_s (bhtn); early alias: xx (btc)
  float* ewbuf = ws + 4*BTC_;   // exp(w) (bhtn); early alias: Wk_h
  float* kkbuf = ws + 5*BTC_;   // kk (bhtn);     early alias: Wv_h
  float* xx    = abuf;
  float* wa1   = ws + 6*BTC_;
  float* g1f   = wa1 + (size_t)BT_*128;
  float* k1c   = g1f + (size_t)BT_*128;
  float* parts = rbuf;
  float* m1f   = vbuf;
  __hip_bfloat16* hb = (__hip_bfloat16*)(k1c + (size_t)BT_*128);
  __hip_bfloat16* xrg_h = hb;
  __hip_bfloat16* xwa_h = hb + 1*CC_;
  __hip_bfloat16* xk_h  = hb + 2*CC_;
  __hip_bfloat16* xv_h  = hb + 3*CC_;
  __hip_bfloat16* Wb    = hb + 4*CC_;
  __hip_bfloat16* WtB   = hb + 5*CC_;
  __hip_bfloat16* Wt_m  = WtB;
  __hip_bfloat16* Wt_wa = WtB + (size_t)128*2048;
  __hip_bfloat16* Wt_g  = WtB + (size_t)2*128*2048;
  __hip_bfloat16* Wt_k  = WtB + (size_t)3*128*2048;
  __hip_bfloat16* xmx_h = xv_h;
  __hip_bfloat16* g_h   = xwa_h;
  __hip_bfloat16* z_h   = xv_h;
  __hip_bfloat16* Wk_h  = (__hip_bfloat16*)ewbuf;
  __hip_bfloat16* Wv_h  = (__hip_bfloat16*)kkbuf;

  dim3 blk(256);
  const int KC = C_/KS_;

  hipMemsetAsync(WtB, 0, (size_t)4*128*2048*2, stream);
  tp_pack<<<dim3(64,4), blk, 0, stream>>>(maa_w1, Wt_m, 128, 0);
  tp_pack<<<dim3(64,2), blk, 0, stream>>>(dw1,  Wt_wa, 64, 0);
  tp_pack<<<dim3(64,1), blk, 0, stream>>>(aw1,  Wt_wa, 16, 64);
  tp_pack<<<dim3(64,1), blk, 0, stream>>>(maw1, Wt_wa, 16, 80);
  tp_pack<<<dim3(64,4), blk, 0, stream>>>(gw1,  Wt_g, 128, 0);
  tp_pack<<<dim3(64,1), blk, 0, stream>>>(kkw1, Wt_k, 16, 0);
  tp_pack<<<dim3(64,1), blk, 0, stream>>>(mkw1, Wt_k, 16, 16);

  shift_kernel<<<(int)(BTC_/256), blk, 0, stream>>>(x, shift, maa_x, xx, xmx_h);

  gemm_sk<<<dim3(BT_/128, KS_), blk, 0, stream>>>(xmx_h, Wt_m, parts, C_, KC);
  reduce_sk<<<BT_*128/256, blk, 0, stream>>>(parts, m1f, 0, 128);

  mix_kernel<<<dim3(BT_/8, C_/256), blk, 0, stream>>>(m1f, maa_w2, x, xx, maa_rg, maa_wa, maa_k, maa_v,
                                                      xrg_h, xwa_h, xk_h, xv_h);
  gemm_sk<<<dim3(BT_/128, KS_), blk, 0, stream>>>(xwa_h, Wt_wa, parts, C_, KC);
  reduce_sk<<<BT_*128/256, blk, 0, stream>>>(parts, wa1, 0, 64);
  gemm_sk<<<dim3(BT_/128, KS_), blk, 0, stream>>>(xrg_h, Wt_g, parts, C_, KC);
  reduce_sk<<<BT_*128/256, blk, 0, stream>>>(parts, g1f, 0, 128);
  gemm_sk<<<dim3(BT_/128, KS_), blk, 0, stream>>>(xk_h, Wt_k, parts, C_, KC);
  reduce_sk<<<BT_*128/256, blk, 0, stream>>>(parts, k1c, 0, 16);

  mm_sk_g<<<dim3(BT_/8, C_/256), blk, 0, stream>>>(g1f, gw2, g_h, 128);

  f2bf_kernel<<<(int)(CC_/256), blk, 0, stream>>>(Wr, Wb, CC_);
  f2bf_kernel<<<(int)(CC_/256), blk, 0, stream>>>(Wk, Wk_h, CC_);
  f2bf_kernel<<<(int)(CC_/256), blk, 0, stream>>>(Wv, Wv_h, CC_);
  gemm_bt_T<<<dim3(BT_/128, C_/128), blk, 0, stream>>>(xrg_h, Wb,   rbuf, C_);
  gemm_bt_T<<<dim3(BT_/128, C_/128), blk, 0, stream>>>(xk_h,  Wk_h, kbuf, C_);
  gemm_bt_T<<<dim3(BT_/128, C_/128), blk, 0, stream>>>(xv_h,  Wv_h, vbuf, C_);

  lora2_kernel<<<dim3(BT_/8, C_/256), blk, 0, stream>>>(wa1, k1c,
                                                        dw2, aw2, maw2, mkw2, kkw2,
                                                        tdecay, aaaaa, misc_a, misc_k,
                                                        kbuf, abuf, ewbuf, kkbuf);
  kknorm_kernel<<<BT_*H_/4, blk, 0, stream>>>(kkbuf, abuf);

  rec_kernel<<<B_*H_*4, dim3(64), 0, stream>>>(rbuf, kbuf, vbuf, ewbuf, kkbuf, abuf, wkv0, out0, outS);

  post_kernel<<<BT_*H_/4, blk, 0, stream>>>(out0, rbuf, kbuf, vbuf, g_h, lnw, lnb, faaaa, z_h);
  f2bf_kernel<<<(int)(CC_/256), blk, 0, stream>>>(Wo, Wb, CC_);
  gemm_bt<<<dim3(BT_/128, C_/128), blk, 0, stream>>>(z_h, Wb, out0, BT_, C_, C_);
  lastx_kernel<<<(B_*C_)/256, blk, 0, stream>>>(x, out1);
}

// Round 7
// 1016.865 us; speedup vs baseline: 1.2505x; 1.0670x over previous
//
#include <hip/hip_runtime.h>
#include <hip/hip_bf16.h>
#include <math.h>

// RWKV-7 Tmix forward, MI355X/gfx950.
// B=2 T=1024 C=2048 H=32 N=64. Outputs: xo [B,T,C], x[:,-1] [B,C], S_final [B,H,N,N].
// R7: rec lane remap (lane = fr*4 + kq) -> cross-lane reductions become quad DPP (VALU),
//     removing all DS-pipe shuffles and their lgkm-drain serialization from the step chain.

#define B_ 2
#define T_ 1024
#define C_ 2048
#define H_ 32
#define BT_ (B_*T_)
#define BTC_ ((size_t)BT_*C_)
#define CC_ ((size_t)C_*C_)
#define KS_ 8            // split-K factor for stage-1 GEMMs
#define CH_ 16           // rec chunk (steps per LDS stage)

typedef __bf16 bf16x8 __attribute__((ext_vector_type(8)));
typedef float f32x4 __attribute__((ext_vector_type(4)));

__device__ __forceinline__ float wave64_sum(float v){
#pragma unroll
  for (int d = 1; d < 64; d <<= 1) v += __shfl_xor(v, d, 64);
  return v;
}

// quad butterfly adds via DPP (VALU pipe, no DS/lgkm involvement)
__device__ __forceinline__ float dpp_add_xor1(float x){
  int j = __builtin_amdgcn_mov_dpp(__float_as_int(x), 0xB1, 0xF, 0xF, true); // quad_perm [1,0,3,2]
  return x + __int_as_float(j);
}
__device__ __forceinline__ float dpp_add_xor2(float x){
  int j = __builtin_amdgcn_mov_dpp(__float_as_int(x), 0x4E, 0xF, 0xF, true); // quad_perm [2,3,0,1]
  return x + __int_as_float(j);
}

// bhtn index helper: (b,t) row r in [BT), channel c in [C) -> [B,H,T,64]
__device__ __forceinline__ size_t bhtn_idx(int r, int c){
  return (((size_t)(r >> 10)*H_ + (c >> 6))*T_ + (r & 1023))*64 + (c & 63);
}

// ---------------- fp32 -> bf16 convert ----------------
__global__ __launch_bounds__(256) void f2bf_kernel(const float* __restrict__ in,
                                                   __hip_bfloat16* __restrict__ out, size_t n){
  size_t i = (size_t)blockIdx.x*256 + threadIdx.x;
  if (i < n) out[i] = __float2bfloat16(in[i]);
}

// ---------------- token shift: xx fp32, xmx bf16 ----------------
__global__ __launch_bounds__(256) void shift_kernel(const float* __restrict__ x,
                                                    const float* __restrict__ shift,
                                                    const float* __restrict__ maa_x,
                                                    float* __restrict__ xx, __hip_bfloat16* __restrict__ xmx_h){
  size_t idx = (size_t)blockIdx.x*256 + threadIdx.x;  // over BTC
  int c = (int)(idx % C_);
  size_t bt = idx / C_;
  int t = (int)(bt % T_);
  int b = (int)(bt / T_);
  float xv = x[idx];
  float prev = (t == 0) ? shift[(size_t)b*C_ + c] : x[idx - C_];
  float d = prev - xv;
  xx[idx] = d;
  xmx_h[idx] = __float2bfloat16(xv + d * maa_x[c]);
}

// ---------------- transpose+convert: W[K=2048,Nsrc] fp32 -> rows [row_off..) of Wt[128,2048] bf16 ----------------
__global__ __launch_bounds__(256) void tp_pack(const float* __restrict__ in, __hip_bfloat16* __restrict__ out,
                                               int Nsrc, int row_off){
  __shared__ float tile[32][33];
  const int t = threadIdx.x;
  const int k0 = blockIdx.x*32, n0 = blockIdx.y*32;
  const int tn = t & 31, tk = t >> 5;  // tk 0..7
#pragma unroll
  for (int q = 0; q < 4; q++){
    int ki = tk + 8*q;
    float v = (n0 + tn < Nsrc) ? in[(size_t)(k0+ki)*Nsrc + n0 + tn] : 0.f;
    tile[tn][ki] = v;
  }
  __syncthreads();
#pragma unroll
  for (int q = 0; q < 4; q++){
    int no = tk + 8*q;
    if (n0 + no < Nsrc)
      out[(size_t)(row_off + n0 + no)*2048 + k0 + tn] = __float2bfloat16(tile[no][tn]);
  }
}

// ---------------- split-K skinny MFMA GEMM: parts[z] = A[128rows x KC] * B[128, KC]^T ----------------
__global__ __launch_bounds__(256) void gemm_sk(const __hip_bfloat16* __restrict__ Ah,
                                               const __hip_bfloat16* __restrict__ Bh,
                                               float* __restrict__ parts, int K, int KC){
  __shared__ __bf16 As[128*40];
  __shared__ __bf16 Bs[128*40];
  const int tid = threadIdx.x;
  const int bm = blockIdx.x*128;
  const int z = blockIdx.y;
  const int wid = tid >> 6, lane = tid & 63;
  const int wr = (wid >> 1)*64, wc = (wid & 1)*64;
  const int fr = lane & 15, kg = lane >> 4;
  const int srow = tid >> 2, sk = (tid & 3)*8;
  f32x4 acc[4][4] = {};
  const int kend = z*KC + KC;
  for (int kt = z*KC; kt < kend; kt += 32){
    __syncthreads();
    uint4 a0 = *(const uint4*)(Ah + (size_t)(bm+srow)*K + kt + sk);
    uint4 a1 = *(const uint4*)(Ah + (size_t)(bm+srow+64)*K + kt + sk);
    uint4 b0 = *(const uint4*)(Bh + (size_t)(srow)*K + kt + sk);
    uint4 b1 = *(const uint4*)(Bh + (size_t)(srow+64)*K + kt + sk);
    *(uint4*)(As + srow*40 + sk)      = a0;
    *(uint4*)(As + (srow+64)*40 + sk) = a1;
    *(uint4*)(Bs + srow*40 + sk)      = b0;
    *(uint4*)(Bs + (srow+64)*40 + sk) = b1;
    __syncthreads();
    bf16x8 af[4], bfr[4];
#pragma unroll
    for (int i = 0; i < 4; i++){
      af[i]  = *(const bf16x8*)(As + (wr + i*16 + fr)*40 + kg*8);
      bfr[i] = *(const bf16x8*)(Bs + (wc + i*16 + fr)*40 + kg*8);
    }
#pragma unroll
    for (int mi = 0; mi < 4; mi++)
#pragma unroll
      for (int ni = 0; ni < 4; ni++)
        acc[mi][ni] = __builtin_amdgcn_mfma_f32_16x16x32_bf16(af[mi], bfr[ni], acc[mi][ni], 0, 0, 0);
  }
  float* Cc = parts + (size_t)z*BT_*128;
  const int orow0 = bm + wr + kg*4;
  const int ocol0 = wc + fr;
#pragma unroll
  for (int mi = 0; mi < 4; mi++)
#pragma unroll
    for (int ni = 0; ni < 4; ni++)
#pragma unroll
      for (int j = 0; j < 4; j++)
        Cc[(size_t)(orow0 + mi*16 + j)*128 + ocol0 + ni*16] = acc[mi][ni][j];
}

// ---------------- reduce split-K parts + fused tanh on column range ----------------
__global__ __launch_bounds__(256) void reduce_sk(const float* __restrict__ parts, float* __restrict__ out,
                                                 int tanh_lo, int tanh_hi){
  size_t idx = (size_t)blockIdx.x*256 + threadIdx.x;  // BT*128
  float s = 0.f;
#pragma unroll
  for (int z = 0; z < KS_; z++) s += parts[(size_t)z*BT_*128 + idx];
  int c = (int)(idx & 127);
  if (c >= tanh_lo && c < tanh_hi) s = tanhf(s);
  out[idx] = s;
}

// ---------------- g = tanh'd g1[BT,128] @ gw2[128,C] -> bf16 ----------------
__global__ __launch_bounds__(256) void mm_sk_g(const float* __restrict__ A, const float* __restrict__ W,
                                               __hip_bfloat16* __restrict__ out, int K){
  const int j = blockIdx.y*256 + threadIdx.x;
  const int i0 = blockIdx.x*8;
  float acc[8] = {0,0,0,0,0,0,0,0};
  for (int k = 0; k < K; k++){
    float wv = W[(size_t)k*C_ + j];
#pragma unroll
    for (int r = 0; r < 8; r++) acc[r] += A[(size_t)(i0+r)*K + k] * wv;
  }
#pragma unroll
  for (int r = 0; r < 8; r++) out[(size_t)(i0+r)*C_ + j] = __float2bfloat16(acc[r]);
}

// ---------------- maa einsum + mix -> bf16 xrg/xwa/xk/xv ----------------
__global__ __launch_bounds__(256) void mix_kernel(
    const float* __restrict__ m1, const float* __restrict__ w2,
    const float* __restrict__ x, const float* __restrict__ xx,
    const float* __restrict__ maa_rg, const float* __restrict__ maa_wa,
    const float* __restrict__ maa_k, const float* __restrict__ maa_v,
    __hip_bfloat16* __restrict__ xrg_h, __hip_bfloat16* __restrict__ xwa_h,
    __hip_bfloat16* __restrict__ xk_h, __hip_bfloat16* __restrict__ xv_h)
{
  const int j = blockIdx.y*256 + threadIdx.x;
  const int i0 = blockIdx.x*8;
  float acc[4][8] = {};
#pragma unroll
  for (int f = 0; f < 4; f++){
    for (int d = 0; d < 32; d++){
      float wv = w2[((size_t)f*32 + d)*C_ + j];
#pragma unroll
      for (int r = 0; r < 8; r++)
        acc[f][r] += m1[(size_t)(i0+r)*128 + f*32 + d] * wv;
    }
  }
  float mrg_ = maa_rg[j], mwa_ = maa_wa[j], mk_ = maa_k[j], mv_ = maa_v[j];
#pragma unroll
  for (int r = 0; r < 8; r++){
    size_t idx = (size_t)(i0+r)*C_ + j;
    float xval = x[idx], xxv = xx[idx];
    xrg_h[idx] = __float2bfloat16(xval + xxv*(mrg_ + acc[0][r]));
    xwa_h[idx] = __float2bfloat16(xval + xxv*(mwa_ + acc[1][r]));
    xk_h[idx]  = __float2bfloat16(xval + xxv*(mk_  + acc[2][r]));
    xv_h[idx]  = __float2bfloat16(xval + xxv*(mv_  + acc[3][r]));
  }
}

// ---------------- bf16 MFMA GEMM: C[M,N] = A[M,K] * B[N,K]^T (fp32 out, btc layout) ----------------
__global__ __launch_bounds__(256) void gemm_bt(const __hip_bfloat16* __restrict__ Ah,
                                               const __hip_bfloat16* __restrict__ Bh,
                                               float* __restrict__ Cc, int M, int Nn, int K){
  __shared__ __bf16 As[128*40];
  __shared__ __bf16 Bs[128*40];
  const int tid = threadIdx.x;
  const int bm = blockIdx.x*128, bn = blockIdx.y*128;
  const int wid = tid >> 6, lane = tid & 63;
  const int wr = (wid >> 1)*64, wc = (wid & 1)*64;
  const int fr = lane & 15, kg = lane >> 4;
  const int srow = tid >> 2, sk = (tid & 3)*8;
  f32x4 acc[4][4] = {};
  for (int kt = 0; kt < K; kt += 32){
    __syncthreads();
    uint4 a0 = *(const uint4*)(Ah + (size_t)(bm+srow)*K + kt + sk);
    uint4 a1 = *(const uint4*)(Ah + (size_t)(bm+srow+64)*K + kt + sk);
    uint4 b0 = *(const uint4*)(Bh + (size_t)(bn+srow)*K + kt + sk);
    uint4 b1 = *(const uint4*)(Bh + (size_t)(bn+srow+64)*K + kt + sk);
    *(uint4*)(As + srow*40 + sk)      = a0;
    *(uint4*)(As + (srow+64)*40 + sk) = a1;
    *(uint4*)(Bs + srow*40 + sk)      = b0;
    *(uint4*)(Bs + (srow+64)*40 + sk) = b1;
    __syncthreads();
    bf16x8 af[4], bfr[4];
#pragma unroll
    for (int i = 0; i < 4; i++){
      af[i]  = *(const bf16x8*)(As + (wr + i*16 + fr)*40 + kg*8);
      bfr[i] = *(const bf16x8*)(Bs + (wc + i*16 + fr)*40 + kg*8);
    }
#pragma unroll
    for (int mi = 0; mi < 4; mi++)
#pragma unroll
      for (int ni = 0; ni < 4; ni++)
        acc[mi][ni] = __builtin_amdgcn_mfma_f32_16x16x32_bf16(af[mi], bfr[ni], acc[mi][ni], 0, 0, 0);
  }
  const int orow0 = bm + wr + kg*4;
  const int ocol0 = bn + wc + fr;
#pragma unroll
  for (int mi = 0; mi < 4; mi++)
#pragma unroll
    for (int ni = 0; ni < 4; ni++)
#pragma unroll
      for (int j = 0; j < 4; j++)
        Cc[(size_t)(orow0 + mi*16 + j)*Nn + ocol0 + ni*16] = acc[mi][ni][j];
}

// ---------------- same GEMM but writes C in [B,H,T,64] (bhtn) layout ----------------
__global__ __launch_bounds__(256) void gemm_bt_T(const __hip_bfloat16* __restrict__ Ah,
                                                 const __hip_bfloat16* __restrict__ Bh,
                                                 float* __restrict__ Cc, int K){
  __shared__ __bf16 As[128*40];
  __shared__ __bf16 Bs[128*40];
  const int tid = threadIdx.x;
  const int bm = blockIdx.x*128, bn = blockIdx.y*128;
  const int wid = tid >> 6, lane = tid & 63;
  const int wr = (wid >> 1)*64, wc = (wid & 1)*64;
  const int fr = lane & 15, kg = lane >> 4;
  const int srow = tid >> 2, sk = (tid & 3)*8;
  f32x4 acc[4][4] = {};
  for (int kt = 0; kt < K; kt += 32){
    __syncthreads();
    uint4 a0 = *(const uint4*)(Ah + (size_t)(bm+srow)*K + kt + sk);
    uint4 a1 = *(const uint4*)(Ah + (size_t)(bm+srow+64)*K + kt + sk);
    uint4 b0 = *(const uint4*)(Bh + (size_t)(bn+srow)*K + kt + sk);
    uint4 b1 = *(const uint4*)(Bh + (size_t)(bn+srow+64)*K + kt + sk);
    *(uint4*)(As + srow*40 + sk)      = a0;
    *(uint4*)(As + (srow+64)*40 + sk) = a1;
    *(uint4*)(Bs + srow*40 + sk)      = b0;
    *(uint4*)(Bs + (srow+64)*40 + sk) = b1;
    __syncthreads();
    bf16x8 af[4], bfr[4];
#pragma unroll
    for (int i = 0; i < 4; i++){
      af[i]  = *(const bf16x8*)(As + (wr + i*16 + fr)*40 + kg*8);
      bfr[i] = *(const bf16x8*)(Bs + (wc + i*16 + fr)*40 + kg*8);
    }
#pragma unroll
    for (int mi = 0; mi < 4; mi++)
#pragma unroll
      for (int ni = 0; ni < 4; ni++)
        acc[mi][ni] = __builtin_amdgcn_mfma_f32_16x16x32_bf16(af[mi], bfr[ni], acc[mi][ni], 0, 0, 0);
  }
  const int r0 = bm + wr + kg*4;
  const int c0 = bn + wc + fr;
#pragma unroll
  for (int mi = 0; mi < 4; mi++)
#pragma unroll
    for (int ni = 0; ni < 4; ni++)
#pragma unroll
      for (int j = 0; j < 4; j++)
        Cc[bhtn_idx(r0 + mi*16 + j, c0 + ni*16)] = acc[mi][ni][j];
}

// ---------------- fused LoRA stage-2 + decay/gates elementwise (writes bhtn) ----------------
// wa1[BT,128]: cols 0..63 = tanh(d1), 64..79 = a1, 80..95 = ma1
// k1c[BT,128]: cols 0..15 = tanh(kk1), 16..31 = mk1
__global__ __launch_bounds__(256) void lora2_kernel(
    const float* __restrict__ wa1, const float* __restrict__ k1c,
    const float* __restrict__ dw2, const float* __restrict__ aw2, const float* __restrict__ maw2,
    const float* __restrict__ mkw2, const float* __restrict__ kkw2,
    const float* __restrict__ td, const float* __restrict__ aaaaa,
    const float* __restrict__ misc_a, const float* __restrict__ misc_k,
    float* __restrict__ k0, float* __restrict__ a_out,
    float* __restrict__ ew_out, float* __restrict__ kk0_out)
{
  const int j = blockIdx.y*256 + threadIdx.x;
  const int i0 = blockIdx.x*8;
  float accW[8] = {}, accA[8] = {}, accMA[8] = {}, accMK[8] = {}, accKK[8] = {};
  for (int k = 0; k < 64; k++){
    float wv = dw2[(size_t)k*C_ + j];
#pragma unroll
    for (int r = 0; r < 8; r++) accW[r] += wa1[(size_t)(i0+r)*128 + k] * wv;
  }
  for (int k = 0; k < 16; k++){
    float w_a  = aw2[(size_t)k*C_ + j];
    float w_ma = maw2[(size_t)k*C_ + j];
    float w_mk = mkw2[(size_t)k*C_ + j];
    float w_kk = kkw2[(size_t)k*C_ + j];
#pragma unroll
    for (int r = 0; r < 8; r++){
      accA[r]  += wa1[(size_t)(i0+r)*128 + 64 + k] * w_a;
      accMA[r] += wa1[(size_t)(i0+r)*128 + 80 + k] * w_ma;
      accKK[r] += k1c[(size_t)(i0+r)*128 + k] * w_kk;
      accMK[r] += k1c[(size_t)(i0+r)*128 + 16 + k] * w_mk;
    }
  }
  float tdv = td[j], aav = aaaaa[j], mav = misc_a[j], mkv = misc_k[j];
#pragma unroll
  for (int r = 0; r < 8; r++){
    size_t idx = bhtn_idx(i0+r, j);
    float u  = tdv + accW[r];
    float w  = -log1pf(expf(-u)) - 0.5f;               // -softplus(-u) - 0.5
    float a  = 1.f/(1.f + expf(-(aav + accA[r])));
    float ma = 1.f/(1.f + expf(-(mav + accMA[r])));
    float mk = 1.f/(1.f + expf(-(mkv + accMK[r])));
    float kv = k0[idx];
    kk0_out[idx] = kv + accKK[r];
    float kn = kv * (ma + a*(1.f - ma)) * expf(fminf(w*mk, 0.f));
    k0[idx] = kn;
    a_out[idx] = a;
    ew_out[idx] = expf(w);
  }
}

// ---------------- kk normalize per head + b = kk*a (in-place; bhtn-compatible) ----------------
__global__ __launch_bounds__(256) void kknorm_kernel(float* __restrict__ kk0, float* __restrict__ a_bs){
  const size_t grp = (size_t)blockIdx.x*4 + (threadIdx.x >> 6);
  const int lane = threadIdx.x & 63;
  const size_t idx = grp*64 + lane;
  float kv = kk0[idx];
  float ss = wave64_sum(kv*kv);
  float nrm = fmaxf(sqrtf(ss), 1e-12f);
  float kkn = kv / nrm;
  kk0[idx] = kkn;
  a_bs[idx] = kkn * a_bs[idx];
}

// ---------------- RWKV-7 recurrence: 256 blocks x 64 threads, LDS ring + quad-DPP reduce ----------------
// Lane map: lane = fr*4 + kq (fr = v-in-chunk 0..15, kq = k-quarter 0..3) so the 4 partial
// owners of one v-column share a quad -> reductions are 2 DPP quad_perm adds (VALU pipe).
__device__ __forceinline__ void gload_lds16(const float* g, float* l){
  __builtin_amdgcn_global_load_lds((const __attribute__((address_space(1))) void*)g,
                                   (__attribute__((address_space(3))) void*)l, 16, 0, 0);
}

__global__ __launch_bounds__(64, 1) void rec_kernel(
    const float* __restrict__ rr, const float* __restrict__ kx,
    const float* __restrict__ vx, const float* __restrict__ ew,
    const float* __restrict__ kkv, const float* __restrict__ bsv,
    const float* __restrict__ s0, float* __restrict__ o, float* __restrict__ sT)
{
  __shared__ __align__(16) float lds[2][6][CH_*64];
  const int blk = blockIdx.x;          // 256 = bh*4 + vc
  const int bh = blk >> 2, vc = blk & 3;
  const int b = bh >> 5, h = bh & 31;
  const int lane = threadIdx.x;
  const int kq = lane & 3;             // k-quarter (quad-local)
  const int fr = lane >> 2;            // v within chunk
  const int kq16 = kq*16;
  const int v = vc*16 + fr;

  float S[16];
  {
    const float* p = s0 + ((size_t)bh*64 + kq16)*64 + v;
#pragma unroll
    for (int i = 0; i < 16; i++) S[i] = p[(size_t)i*64];
  }

  const size_t sb = (size_t)bh*T_*64;  // stream base (bhtn)
  const float* g0 = kkv + sb;  // a
  const float* g1 = ew  + sb;  // e
  const float* g2 = kx  + sb;  // k
  const float* g3 = bsv + sb;  // b
  const float* g4 = rr  + sb;  // r
  const float* g5 = vx  + sb;  // v
  float* ob = o + (size_t)b*T_*C_ + h*64 + v;   // + t*C_

#define STAGE(c, buf) do{ \
    const size_t co_ = (size_t)(c)*(CH_*64) + lane*4; \
    _Pragma("unroll") \
    for (int j_ = 0; j_ < 4; j_++){ \
      gload_lds16(g0 + co_ + j_*256, &lds[buf][0][j_*256]); \
      gload_lds16(g1 + co_ + j_*256, &lds[buf][1][j_*256]); \
      gload_lds16(g2 + co_ + j_*256, &lds[buf][2][j_*256]); \
      gload_lds16(g3 + co_ + j_*256, &lds[buf][3][j_*256]); \
      gload_lds16(g4 + co_ + j_*256, &lds[buf][4][j_*256]); \
      gload_lds16(g5 + co_ + j_*256, &lds[buf][5][j_*256]); \
    } }while(0)

  STAGE(0, 0);
  const int NCH = T_/CH_;              // 64
  for (int c = 0; c < NCH; c++){
    const int cn = (c+1 < NCH) ? c+1 : c;   // harmless re-stage on last iter
    STAGE(cn, (c+1)&1);
    __builtin_amdgcn_s_waitcnt(0x4F78);     // vmcnt(24): chunk c's 24 loads complete
    __builtin_amdgcn_sched_barrier(0);      // keep ds_reads below the wait
    const int buf = c & 1;
#pragma unroll 4
    for (int s = 0; s < CH_; s++){
      const int so = s*64 + kq16;
      float4 A[4], E[4], Kk[4], Bv[4], R[4];
#pragma unroll
      for (int q = 0; q < 4; q++){
        A[q]  = *(const float4*)(&lds[buf][0][so + 4*q]);
        E[q]  = *(const float4*)(&lds[buf][1][so + 4*q]);
        Kk[q] = *(const float4*)(&lds[buf][2][so + 4*q]);
        Bv[q] = *(const float4*)(&lds[buf][3][so + 4*q]);
        R[q]  = *(const float4*)(&lds[buf][4][so + 4*q]);
      }
      const float vt = lds[buf][5][s*64 + v];
      float p0, p1, p2, p3;
      p0  = A[0].x*S[0];  p0 += A[0].y*S[1];  p0 += A[0].z*S[2];  p0 += A[0].w*S[3];
      p1  = A[1].x*S[4];  p1 += A[1].y*S[5];  p1 += A[1].z*S[6];  p1 += A[1].w*S[7];
      p2  = A[2].x*S[8];  p2 += A[2].y*S[9];  p2 += A[2].z*S[10]; p2 += A[2].w*S[11];
      p3  = A[3].x*S[12]; p3 += A[3].y*S[13]; p3 += A[3].z*S[14]; p3 += A[3].w*S[15];
      float sap = (p0+p1) + (p2+p3);
      sap = dpp_add_xor1(sap);
      sap = dpp_add_xor2(sap);
      const float sa = -sap;               // a_t = -kk
      float o0, o1, o2, o3;
      S[0]  = S[0] *E[0].x + Kk[0].x*vt + Bv[0].x*sa; o0  = R[0].x*S[0];
      S[1]  = S[1] *E[0].y + Kk[0].y*vt + Bv[0].y*sa; o0 += R[0].y*S[1];
      S[2]  = S[2] *E[0].z + Kk[0].z*vt + Bv[0].z*sa; o0 += R[0].z*S[2];
      S[3]  = S[3] *E[0].w + Kk[0].w*vt + Bv[0].w*sa; o0 += R[0].w*S[3];
      S[4]  = S[4] *E[1].x + Kk[1].x*vt + Bv[1].x*sa; o1  = R[1].x*S[4];
      S[5]  = S[5] *E[1].y + Kk[1].y*vt + Bv[1].y*sa; o1 += R[1].y*S[5];
      S[6]  = S[6] *E[1].z + Kk[1].z*vt + Bv[1].z*sa; o1 += R[1].z*S[6];
      S[7]  = S[7] *E[1].w + Kk[1].w*vt + Bv[1].w*sa; o1 += R[1].w*S[7];
      S[8]  = S[8] *E[2].x + Kk[2].x*vt + Bv[2].x*sa; o2  = R[2].x*S[8];
      S[9]  = S[9] *E[2].y + Kk[2].y*vt + Bv[2].y*sa; o2 += R[2].y*S[9];
      S[10] = S[10]*E[2].z + Kk[2].z*vt + Bv[2].z*sa; o2 += R[2].z*S[10];
      S[11] = S[11]*E[2].w + Kk[2].w*vt + Bv[2].w*sa; o2 += R[2].w*S[11];
      S[12] = S[12]*E[3].x + Kk[3].x*vt + Bv[3].x*sa; o3  = R[3].x*S[12];
      S[13] = S[13]*E[3].y + Kk[3].y*vt + Bv[3].y*sa; o3 += R[3].y*S[13];
      S[14] = S[14]*E[3].z + Kk[3].z*vt + Bv[3].z*sa; o3 += R[3].z*S[14];
      S[15] = S[15]*E[3].w + Kk[3].w*vt + Bv[3].w*sa; o3 += R[3].w*S[15];
      float op = (o0+o1) + (o2+o3);
      op = dpp_add_xor1(op);
      op = dpp_add_xor2(op);
      if (kq == 0) ob[(size_t)(c*CH_ + s)*C_] = op;
    }
  }
#undef STAGE
  float* p = sT + ((size_t)bh*64 + kq16)*64 + v;
#pragma unroll
  for (int i = 0; i < 16; i++) p[(size_t)i*64] = S[i];
}

// ---------------- GroupNorm + faaaa term + *g -> z (bf16) ----------------
// o,g,z in btc layout; r,k,v in bhtn layout.
__global__ __launch_bounds__(256) void post_kernel(
    const float* __restrict__ o, const float* __restrict__ r, const float* __restrict__ k,
    const float* __restrict__ v, const __hip_bfloat16* __restrict__ g,
    const float* __restrict__ lnw, const float* __restrict__ lnb,
    const float* __restrict__ faaaa, __hip_bfloat16* __restrict__ z_h)
{
  const size_t grp = (size_t)blockIdx.x*4 + (threadIdx.x >> 6);  // bt*H + h
  const int lane = threadIdx.x & 63;
  const int h = (int)(grp & (H_-1));
  const int bt = (int)(grp >> 5);
  const size_t idx  = grp*64 + lane;                              // btc
  const size_t idx2 = (((size_t)(bt >> 10)*H_ + h)*T_ + (bt & 1023))*64 + lane;  // bhtn
  const int ci = h*64 + lane;
  float y = o[idx];
  float mu = wave64_sum(y) * (1.f/64.f);
  float d = y - mu;
  float var = wave64_sum(d*d) * (1.f/64.f);
  float yn = d * rsqrtf(var + 64e-5f) * lnw[ci] + lnb[ci];
  float s = wave64_sum(r[idx2]*k[idx2]*faaaa[ci]);
  float xo = yn + s*v[idx2];
  z_h[idx] = __float2bfloat16(xo * __bfloat162float(g[idx]));
}

// ---------------- x[:, -1] ----------------
__global__ __launch_bounds__(256) void lastx_kernel(const float* __restrict__ x, float* __restrict__ out1){
  int idx = blockIdx.x*256 + threadIdx.x;   // B*C
  int b = idx / C_, c = idx % C_;
  out1[idx] = x[((size_t)b*T_ + (T_-1))*C_ + c];
}

extern "C" void kernel_launch(void* const* d_in, const int* in_sizes, int n_in,
                              void* d_out, int out_size, void* d_ws, size_t ws_size,
                              hipStream_t stream){
  (void)in_sizes; (void)n_in; (void)out_size;
  const float* x      = (const float*)d_in[0];
  const float* shift  = (const float*)d_in[1];
  const float* wkv0   = (const float*)d_in[2];
  const float* maa_x  = (const float*)d_in[3];
  const float* maa_rg = (const float*)d_in[4];
  const float* maa_wa = (const float*)d_in[5];
  const float* maa_k  = (const float*)d_in[6];
  const float* maa_v  = (const float*)d_in[7];
  const float* maa_w1 = (const float*)d_in[8];
  const float* maa_w2 = (const float*)d_in[9];
  const float* tdecay = (const float*)d_in[10];
  const float* dw1    = (const float*)d_in[11];
  const float* dw2    = (const float*)d_in[12];
  const float* faaaa  = (const float*)d_in[13];
  const float* aaaaa  = (const float*)d_in[14];
  const float* aw1    = (const float*)d_in[15];
  const float* aw2    = (const float*)d_in[16];
  const float* kkw1   = (const float*)d_in[17];
  const float* kkw2   = (const float*)d_in[18];
  const float* gw1    = (const float*)d_in[19];
  const float* gw2    = (const float*)d_in[20];
  const float* maw1   = (const float*)d_in[21];
  const float* maw2   = (const float*)d_in[22];
  const float* misc_a = (const float*)d_in[23];
  const float* mkw1   = (const float*)d_in[24];
  const float* mkw2   = (const float*)d_in[25];
  const float* misc_k = (const float*)d_in[26];
  const float* Wr     = (const float*)d_in[27];
  const float* Wk     = (const float*)d_in[28];
  const float* Wv     = (const float*)d_in[29];
  const float* Wo     = (const float*)d_in[30];
  const float* lnw    = (const float*)d_in[31];
  const float* lnb    = (const float*)d_in[32];

  float* out0 = (float*)d_out;                 // [B,T,C]  (also holds o pre-epilogue)
  float* out1 = out0 + BTC_;                   // [B,C]
  float* outS = out1 + (size_t)B_*C_;          // [B,H,N,N]

  const size_t NEEDED = (6*BTC_ + (size_t)3*BT_*128)*4 + 5*CC_*2 + (size_t)4*128*2048*2;
  if (ws_size < NEEDED) return;

  float* ws = (float*)d_ws;
  float* rbuf  = ws;            // bhtn
  float* kbuf  = ws + 1*BTC_;   // bhtn
  float* vbuf  = ws + 2*BTC_;   // bhtn
  float* abuf  = ws + 3*BTC_;   // a -> b_s (bhtn); early alias: xx (btc)
  float* ewbuf = ws + 4*BTC_;   // exp(w) (bhtn); early alias: Wk_h
  float* kkbuf = ws + 5*BTC_;   // kk (bhtn);     early alias: Wv_h
  float* xx    = abuf;
  float* wa1   = ws + 6*BTC_;
  float* g1f   = wa1 + (size_t)BT_*128;
  float* k1c   = g1f + (size_t)BT_*128;
  float* parts = rbuf;
  float* m1f   = vbuf;
  __hip_bfloat16* hb = (__hip_bfloat16*)(k1c + (size_t)BT_*128);
  __hip_bfloat16* xrg_h = hb;
  __hip_bfloat16* xwa_h = hb + 1*CC_;
  __hip_bfloat16* xk_h  = hb + 2*CC_;
  __hip_bfloat16* xv_h  = hb + 3*CC_;
  __hip_bfloat16* Wb    = hb + 4*CC_;
  __hip_bfloat16* WtB   = hb + 5*CC_;
  __hip_bfloat16* Wt_m  = WtB;
  __hip_bfloat16* Wt_wa = WtB + (size_t)128*2048;
  __hip_bfloat16* Wt_g  = WtB + (size_t)2*128*2048;
  __hip_bfloat16* Wt_k  = WtB + (size_t)3*128*2048;
  __hip_bfloat16* xmx_h = xv_h;
  __hip_bfloat16* g_h   = xwa_h;
  __hip_bfloat16* z_h   = xv_h;
  __hip_bfloat16* Wk_h  = (__hip_bfloat16*)ewbuf;
  __hip_bfloat16* Wv_h  = (__hip_bfloat16*)kkbuf;

  dim3 blk(256);
  const int KC = C_/KS_;

  hipMemsetAsync(WtB, 0, (size_t)4*128*2048*2, stream);
  tp_pack<<<dim3(64,4), blk, 0, stream>>>(maa_w1, Wt_m, 128, 0);
  tp_pack<<<dim3(64,2), blk, 0, stream>>>(dw1,  Wt_wa, 64, 0);
  tp_pack<<<dim3(64,1), blk, 0, stream>>>(aw1,  Wt_wa, 16, 64);
  tp_pack<<<dim3(64,1), blk, 0, stream>>>(maw1, Wt_wa, 16, 80);
  tp_pack<<<dim3(64,4), blk, 0, stream>>>(gw1,  Wt_g, 128, 0);
  tp_pack<<<dim3(64,1), blk, 0, stream>>>(kkw1, Wt_k, 16, 0);
  tp_pack<<<dim3(64,1), blk, 0, stream>>>(mkw1, Wt_k, 16, 16);

  shift_kernel<<<(int)(BTC_/256), blk, 0, stream>>>(x, shift, maa_x, xx, xmx_h);

  gemm_sk<<<dim3(BT_/128, KS_), blk, 0, stream>>>(xmx_h, Wt_m, parts, C_, KC);
  reduce_sk<<<BT_*128/256, blk, 0, stream>>>(parts, m1f, 0, 128);

  mix_kernel<<<dim3(BT_/8, C_/256), blk, 0, stream>>>(m1f, maa_w2, x, xx, maa_rg, maa_wa, maa_k, maa_v,
                                                      xrg_h, xwa_h, xk_h, xv_h);
  gemm_sk<<<dim3(BT_/128, KS_), blk, 0, stream>>>(xwa_h, Wt_wa, parts, C_, KC);
  reduce_sk<<<BT_*128/256, blk, 0, stream>>>(parts, wa1, 0, 64);
  gemm_sk<<<dim3(BT_/128, KS_), blk, 0, stream>>>(xrg_h, Wt_g, parts, C_, KC);
  reduce_sk<<<BT_*128/256, blk, 0, stream>>>(parts, g1f, 0, 128);
  gemm_sk<<<dim3(BT_/128, KS_), blk, 0, stream>>>(xk_h, Wt_k, parts, C_, KC);
  reduce_sk<<<BT_*128/256, blk, 0, stream>>>(parts, k1c, 0, 16);

  mm_sk_g<<<dim3(BT_/8, C_/256), blk, 0, stream>>>(g1f, gw2, g_h, 128);

  f2bf_kernel<<<(int)(CC_/256), blk, 0, stream>>>(Wr, Wb, CC_);
  f2bf_kernel<<<(int)(CC_/256), blk, 0, stream>>>(Wk, Wk_h, CC_);
  f2bf_kernel<<<(int)(CC_/256), blk, 0, stream>>>(Wv, Wv_h, CC_);
  gemm_bt_T<<<dim3(BT_/128, C_/128), blk, 0, stream>>>(xrg_h, Wb,   rbuf, C_);
  gemm_bt_T<<<dim3(BT_/128, C_/128), blk, 0, stream>>>(xk_h,  Wk_h, kbuf, C_);
  gemm_bt_T<<<dim3(BT_/128, C_/128), blk, 0, stream>>>(xv_h,  Wv_h, vbuf, C_);

  lora2_kernel<<<dim3(BT_/8, C_/256), blk, 0, stream>>>(wa1, k1c,
                                                        dw2, aw2, maw2, mkw2, kkw2,
                                                        tdecay, aaaaa, misc_a, misc_k,
                                                        kbuf, abuf, ewbuf, kkbuf);
  kknorm_kernel<<<BT_*H_/4, blk, 0, stream>>>(kkbuf, abuf);

  rec_kernel<<<B_*H_*4, dim3(64), 0, stream>>>(rbuf, kbuf, vbuf, ewbuf, kkbuf, abuf, wkv0, out0, outS);

  post_kernel<<<BT_*H_/4, blk, 0, stream>>>(out0, rbuf, kbuf, vbuf, g_h, lnw, lnb, faaaa, z_h);
  f2bf_kernel<<<(int)(CC_/256), blk, 0, stream>>>(Wo, Wb, CC_);
  gemm_bt<<<dim3(BT_/128, C_/128), blk, 0, stream>>>(z_h, Wb, out0, BT_, C_, C_);
  lastx_kernel<<<(B_*C_)/256, blk, 0, stream>>>(x, out1);
}